// Round 2
// baseline (916.567 us; speedup 1.0000x reference)
//
#include <hip/hip_runtime.h>
#include <math.h>
#include <limits.h>

// Problem constants
// B=4096, N=196, D=32, M=12, NH=4, DH=8, H=W=14
// outputs (flat f32): Z[4096*32] | A_maps[4096*12*196] | head_energy[4096*12*4] | S[4096*12*32] | topk_mass[4096*12]

typedef float f32x4 __attribute__((ext_vector_type(4)));

__device__ __forceinline__ float dot4(float4 a, float4 b){
  return a.x*b.x + a.y*b.y + a.z*b.z + a.w*b.w;
}

// ---- DPP-based wave64 reductions (VALU pipe, no LDS) ----
template<int CTRL>
__device__ __forceinline__ float fdpp(float x, float id){
  return __builtin_bit_cast(float,
    __builtin_amdgcn_update_dpp(__builtin_bit_cast(int, id),
                                __builtin_bit_cast(int, x),
                                CTRL, 0xF, 0xF, false));
}
template<int CTRL>
__device__ __forceinline__ int idpp(int x, int id){
  return __builtin_amdgcn_update_dpp(id, x, CTRL, 0xF, 0xF, false);
}
// full-wave max, result broadcast to all lanes (via SGPR readlane 63)
__device__ __forceinline__ float wmax_all(float x){
  const float ID = -1e30f;
  x = fmaxf(x, fdpp<0x111>(x, ID)); // row_shr:1
  x = fmaxf(x, fdpp<0x112>(x, ID)); // row_shr:2
  x = fmaxf(x, fdpp<0x114>(x, ID)); // row_shr:4
  x = fmaxf(x, fdpp<0x118>(x, ID)); // row_shr:8
  x = fmaxf(x, fdpp<0x142>(x, ID)); // row_bcast15
  x = fmaxf(x, fdpp<0x143>(x, ID)); // row_bcast31
  return __builtin_bit_cast(float, __builtin_amdgcn_readlane(__builtin_bit_cast(int, x), 63));
}
__device__ __forceinline__ float wsum_all(float x){
  x += fdpp<0x111>(x, 0.f);
  x += fdpp<0x112>(x, 0.f);
  x += fdpp<0x114>(x, 0.f);
  x += fdpp<0x118>(x, 0.f);
  x += fdpp<0x142>(x, 0.f);
  x += fdpp<0x143>(x, 0.f);
  return __builtin_bit_cast(float, __builtin_amdgcn_readlane(__builtin_bit_cast(int, x), 63));
}
__device__ __forceinline__ int wimax_all(int x){
  const int ID = 0; // keys are >= 0
  x = max(x, idpp<0x111>(x, ID));
  x = max(x, idpp<0x112>(x, ID));
  x = max(x, idpp<0x114>(x, ID));
  x = max(x, idpp<0x118>(x, ID));
  x = max(x, idpp<0x142>(x, ID));
  x = max(x, idpp<0x143>(x, ID));
  return __builtin_amdgcn_readlane(x, 63);
}

// ---------------- prologue: G = (Q Wq^T reshaped) * Wk / sqrt(8), rpbc gather ----------------
// ws layout (floats): G[1536] | rpbc[9408]
__global__ void prologue_kernel(const float* __restrict__ Q, const float* __restrict__ Wq,
                                const float* __restrict__ Wk, const float* __restrict__ rpb,
                                const float* __restrict__ qc, const float* __restrict__ kc,
                                float* __restrict__ ws)
{
  __shared__ float Qp[384];
  const int tid = threadIdx.x;
  const int bid = blockIdx.x;
  float* G = ws;
  float* rpbc = ws + 1536;

  if (bid == 0){
    for (int i = tid; i < 384; i += 256){
      int m = i >> 5, d = i & 31;
      float a = 0.f;
      #pragma unroll
      for (int c = 0; c < 32; ++c) a += Q[m*32+c] * Wq[d*32+c];
      Qp[i] = a;
    }
    __syncthreads();
    const float s = 0.35355339059327373f; // 1/sqrt(8)
    for (int i = tid; i < 1536; i += 256){
      int hm = i >> 5, c = i & 31;
      int h = hm / 12, m = hm - 12*h;
      float a = 0.f;
      #pragma unroll
      for (int dh = 0; dh < 8; ++dh) a += Qp[m*32 + h*8 + dh] * Wk[(h*8+dh)*32 + c];
      G[i] = a * s;
    }
  }
  // rpbc split across all 40 blocks (40*256 = 10240 >= 9408)
  int i = bid*256 + tid;
  if (i < 9408){
    int hm = i / 196, n = i - 196*hm;
    int h = hm / 12, m = hm - 12*h;
    float dy = qc[2*m]   - kc[2*n];
    float dx = qc[2*m+1] - kc[2*n+1];
    int iy = (int)rintf(dy) + 13; iy = iy < 0 ? 0 : (iy > 26 ? 26 : iy);
    int ix = (int)rintf(dx) + 13; ix = ix < 0 ? 0 : (ix > 26 ? 26 : ix);
    rpbc[i] = rpb[h*729 + iy*27 + ix];
  }
}

// ---------------- main fused kernel: one block per batch element ----------------
__global__ __launch_bounds__(256, 2) void slotpool_main(
    const float* __restrict__ T, const float* __restrict__ Wv, const float* __restrict__ Wp,
    const float* __restrict__ bp, const float* __restrict__ ws, float* __restrict__ out)
{
  __shared__ __align__(16) float Ts[196*36];   // T rows, padded stride 36
  __shared__ __align__(16) float As[48*196];   // A[h*12+m][n]
  __shared__ __align__(16) float GU[1536];     // G then (reused) U
  __shared__ __align__(16) float Ss[384];      // S for this b (m*32+d)
  __shared__ float red[256];

  const int b    = blockIdx.x;
  const int tid  = threadIdx.x;
  const int lane = tid & 63;
  const int h    = tid >> 6;   // wave id == head in step B

  float* outZ = out;                       // [4096][32]
  float* outA = out + 131072;              // [4096][12][196]
  float* outE = out + 9764864;             // [4096][12][4]
  float* outS = out + 9961472;             // [4096][12][32]
  float* outK = out + 11534336;            // [4096][12]

  const float* G    = ws;
  const float* rpbc = ws + 1536;

  // ---- A: stage T (nontemporal: streamed once, keep L2 for Wp/rpbc/G) ----
  const f32x4* Tg = (const f32x4*)(T + (size_t)b * 6272);
  for (int i = tid; i < 1568; i += 256){
    int n = i >> 3, c4 = i & 7;
    f32x4 v = __builtin_nontemporal_load(Tg + i);
    *(f32x4*)&Ts[n*36 + c4*4] = v;
  }
  for (int i = tid; i < 384; i += 256) ((float4*)GU)[i] = ((const float4*)G)[i];
  __syncthreads();

  // ---- B: content (T @ G^T) + rpb, softmax over n, entropy ----
  const int n0 = lane, n1 = lane + 64, n2 = lane + 128, n3 = lane + 192;
  const bool v3 = (n3 < 196);
  const int n3c = v3 ? n3 : 195;

  float acc[12][4];
  #pragma unroll
  for (int m = 0; m < 12; ++m){
    const float* rrow = rpbc + (h*12 + m) * 196;
    acc[m][0] = rrow[n0]; acc[m][1] = rrow[n1];
    acc[m][2] = rrow[n2]; acc[m][3] = rrow[n3c];
  }
  #pragma unroll
  for (int c4 = 0; c4 < 8; ++c4){
    float4 t0 = *(const float4*)&Ts[n0 *36 + c4*4];
    float4 t1 = *(const float4*)&Ts[n1 *36 + c4*4];
    float4 t2 = *(const float4*)&Ts[n2 *36 + c4*4];
    float4 t3 = *(const float4*)&Ts[n3c*36 + c4*4];
    #pragma unroll
    for (int m = 0; m < 12; ++m){
      float4 g = *(const float4*)&GU[(h*12 + m)*32 + c4*4];
      acc[m][0] += dot4(t0, g);
      acc[m][1] += dot4(t1, g);
      acc[m][2] += dot4(t2, g);
      acc[m][3] += dot4(t3, g);
    }
  }
  const float LOGN_INV = 0.18946127f; // 1/ln(196)
  #pragma unroll
  for (int m = 0; m < 12; ++m){
    float x0 = acc[m][0], x1 = acc[m][1], x2 = acc[m][2];
    float x3 = v3 ? acc[m][3] : -1e30f;
    float mx = wmax_all(fmaxf(fmaxf(x0, x1), fmaxf(x2, x3)));
    float e0 = __expf(x0 - mx), e1 = __expf(x1 - mx), e2 = __expf(x2 - mx);
    float e3 = v3 ? __expf(x3 - mx) : 0.f;
    float s  = wsum_all(e0 + e1 + e2 + e3);
    float t  = wsum_all((x0-mx)*e0 + (x1-mx)*e1 + (x2-mx)*e2 + (v3 ? (x3-mx)*e3 : 0.f));
    float inv = 1.f / s;
    float* arow = As + (h*12 + m) * 196;
    arow[n0] = e0 * inv; arow[n1] = e1 * inv; arow[n2] = e2 * inv;
    if (v3) arow[n3] = e3 * inv;
    if (lane == 0)
      outE[(size_t)b*48 + m*4 + h] = 1.0f + (t*inv - __logf(s)) * LOGN_INV;
  }
  __syncthreads();

  // ---- C: A_avg over heads, A_maps out, top-9 mass (packed int-key argmax) ----
  #pragma unroll
  for (int mi = 0; mi < 3; ++mi){
    int m = h + mi*4;
    float av0 = 0.25f*(As[m*196+n0] + As[(12+m)*196+n0] + As[(24+m)*196+n0] + As[(36+m)*196+n0]);
    float av1 = 0.25f*(As[m*196+n1] + As[(12+m)*196+n1] + As[(24+m)*196+n1] + As[(36+m)*196+n1]);
    float av2 = 0.25f*(As[m*196+n2] + As[(12+m)*196+n2] + As[(24+m)*196+n2] + As[(36+m)*196+n2]);
    float av3 = 0.25f*(As[m*196+n3c] + As[(12+m)*196+n3c] + As[(24+m)*196+n3c] + As[(36+m)*196+n3c]);
    float* amrow = outA + (size_t)b*2352 + m*196;
    __builtin_nontemporal_store(av0, amrow + n0);
    __builtin_nontemporal_store(av1, amrow + n1);
    __builtin_nontemporal_store(av2, amrow + n2);
    if (v3) __builtin_nontemporal_store(av3, amrow + n3);

    // keys: value bits (positive) with low 8 bits replaced by (lane<<2 | slot)
    int k0 = (__builtin_bit_cast(int, av0) & ~0xFF) | (lane << 2) | 0;
    int k1 = (__builtin_bit_cast(int, av1) & ~0xFF) | (lane << 2) | 1;
    int k2 = (__builtin_bit_cast(int, av2) & ~0xFF) | (lane << 2) | 2;
    int k3 = v3 ? ((__builtin_bit_cast(int, av3) & ~0xFF) | (lane << 2) | 3) : 0;

    float mass = 0.f;
    #pragma unroll
    for (int k = 0; k < 9; ++k){
      int g = wimax_all(max(max(k0, k1), max(k2, k3)));
      mass += __builtin_bit_cast(float, g & ~0xFF);
      int gl = (g >> 2) & 63, gq = g & 3;
      if (lane == gl){
        if      (gq == 0) k0 = 0;
        else if (gq == 1) k1 = 0;
        else if (gq == 2) k2 = 0;
        else              k3 = 0;
      }
    }
    if (lane == 0) __builtin_nontemporal_store(mass, outK + (size_t)b*12 + m);
  }

  // ---- D: U[mh][c] = sum_n A[mh][n] * T[n][c]   (overwrites GU; G is dead) ----
  {
    const int c4  = tid & 7;
    const int mh0 = tid >> 3;  // 0..31
    #pragma unroll
    for (int k = 0; k < 2; ++k){
      int mh = mh0 + 32*k;
      if (mh < 48){
        const float4* Arow = (const float4*)(As + mh*196);
        float4 u = {0.f, 0.f, 0.f, 0.f};
        for (int q = 0; q < 49; ++q){
          float4 a = Arow[q];
          const float* tb = &Ts[(4*q)*36 + c4*4];
          float4 p0 = *(const float4*)(tb);
          float4 p1 = *(const float4*)(tb + 36);
          float4 p2 = *(const float4*)(tb + 72);
          float4 p3 = *(const float4*)(tb + 108);
          u.x += a.x*p0.x + a.y*p1.x + a.z*p2.x + a.w*p3.x;
          u.y += a.x*p0.y + a.y*p1.y + a.z*p2.y + a.w*p3.y;
          u.z += a.x*p0.z + a.y*p1.z + a.z*p2.z + a.w*p3.z;
          u.w += a.x*p0.w + a.y*p1.w + a.z*p2.w + a.w*p3.w;
        }
        *(float4*)&GU[mh*32 + c4*4] = u;
      }
    }
  }
  __syncthreads();

  // ---- E: S[m][d] = sum_c U[(d>>3)*12+m][c] * Wv[d][c]; write S out ----
  for (int md = tid; md < 384; md += 256){
    int m = md >> 5, d = md & 31, hh = d >> 3;
    const float4* Urow = (const float4*)(GU + (hh*12 + m)*32);
    const float4* Wvr  = (const float4*)(Wv + d*32);
    float a = 0.f;
    #pragma unroll
    for (int q = 0; q < 8; ++q) a += dot4(Urow[q], Wvr[q]);
    Ss[md] = a;
    __builtin_nontemporal_store(a, outS + (size_t)b*384 + md);
  }
  __syncthreads();

  // ---- F: Z[d] = bp[d] + sum_j Wp[d][j] * Ss[j]  (float4, L2-hot Wp) ----
  {
    int d = tid >> 3, j4 = tid & 7;
    const float4* Wp4 = (const float4*)(Wp + d*384);
    const float4* Ss4 = (const float4*)Ss;
    float a = 0.f;
    #pragma unroll
    for (int jj = 0; jj < 12; ++jj){
      int j = j4 + jj*8;
      a += dot4(Wp4[j], Ss4[j]);
    }
    red[tid] = a;
  }
  __syncthreads();
  if (tid < 32){
    float a = bp[tid];
    #pragma unroll
    for (int k = 0; k < 8; ++k) a += red[tid*8 + k];
    __builtin_nontemporal_store(a, outZ + (size_t)b*32 + tid);
  }
}

extern "C" void kernel_launch(void* const* d_in, const int* in_sizes, int n_in,
                              void* d_out, int out_size, void* d_ws, size_t ws_size,
                              hipStream_t stream)
{
  const float* T    = (const float*)d_in[0];
  const float* Q    = (const float*)d_in[1];
  const float* Wq   = (const float*)d_in[2];
  const float* Wk   = (const float*)d_in[3];
  const float* Wv   = (const float*)d_in[4];
  const float* Wp   = (const float*)d_in[5];
  const float* bp   = (const float*)d_in[6];
  const float* rpb  = (const float*)d_in[7];
  const float* qc   = (const float*)d_in[8];
  const float* kc   = (const float*)d_in[9];
  float* ws  = (float*)d_ws;
  float* outp = (float*)d_out;

  prologue_kernel<<<40, 256, 0, stream>>>(Q, Wq, Wk, rpb, qc, kc, ws);
  slotpool_main<<<4096, 256, 0, stream>>>(T, Wv, Wp, bp, ws, outp);
}

// Round 3
// 186.895 us; speedup vs baseline: 4.9042x; 4.9042x over previous
//
#include <hip/hip_runtime.h>
#include <math.h>

// B=4096, N=196, D=32, M=12, NH=4, DH=8, H=W=14
// outputs (flat f32): Z[4096*32] | A_maps[4096*12*196] | head_energy[4096*12*4] | S[4096*12*32] | topk_mass[4096*12]
// ws layout: G32[1536 f32] @0 | G16[1536 f16] @ float-off 1536 | rpbc[9408 f32] @ float-off 2304
//            | Aws fp16 [4096][48][200] @ byte-off 49152  (needs 78,692,352 B total)

typedef float f32x4 __attribute__((ext_vector_type(4)));
typedef _Float16 h2 __attribute__((ext_vector_type(2)));
typedef _Float16 h8 __attribute__((ext_vector_type(8)));

__device__ __forceinline__ float dot4(float4 a, float4 b){
  return a.x*b.x + a.y*b.y + a.z*b.z + a.w*b.w;
}

#define H2S(v,k) __builtin_shufflevector((v), (v), 2*(k), 2*(k)+1)

#if __has_builtin(__builtin_amdgcn_fdot2)
__device__ __forceinline__ float FDOT2(h2 a, h2 b, float c){
  return __builtin_amdgcn_fdot2(a, b, c, false);
}
#else
__device__ __forceinline__ float FDOT2(h2 a, h2 b, float c){
  return c + (float)a[0]*(float)b[0] + (float)a[1]*(float)b[1];
}
#endif

__device__ __forceinline__ float dot8h(h8 a, h8 b, float c){
  c = FDOT2(H2S(a,0), H2S(b,0), c);
  c = FDOT2(H2S(a,1), H2S(b,1), c);
  c = FDOT2(H2S(a,2), H2S(b,2), c);
  c = FDOT2(H2S(a,3), H2S(b,3), c);
  return c;
}

// ---- DPP-based wave64 reductions (VALU pipe, no LDS) ----
template<int CTRL>
__device__ __forceinline__ float fdpp(float x, float id){
  return __builtin_bit_cast(float,
    __builtin_amdgcn_update_dpp(__builtin_bit_cast(int, id),
                                __builtin_bit_cast(int, x),
                                CTRL, 0xF, 0xF, false));
}
template<int CTRL>
__device__ __forceinline__ int idpp(int x, int id){
  return __builtin_amdgcn_update_dpp(id, x, CTRL, 0xF, 0xF, false);
}
__device__ __forceinline__ float wmax_all(float x){
  const float ID = -1e30f;
  x = fmaxf(x, fdpp<0x111>(x, ID));
  x = fmaxf(x, fdpp<0x112>(x, ID));
  x = fmaxf(x, fdpp<0x114>(x, ID));
  x = fmaxf(x, fdpp<0x118>(x, ID));
  x = fmaxf(x, fdpp<0x142>(x, ID));
  x = fmaxf(x, fdpp<0x143>(x, ID));
  return __builtin_bit_cast(float, __builtin_amdgcn_readlane(__builtin_bit_cast(int, x), 63));
}
__device__ __forceinline__ float wsum_all(float x){
  x += fdpp<0x111>(x, 0.f);
  x += fdpp<0x112>(x, 0.f);
  x += fdpp<0x114>(x, 0.f);
  x += fdpp<0x118>(x, 0.f);
  x += fdpp<0x142>(x, 0.f);
  x += fdpp<0x143>(x, 0.f);
  return __builtin_bit_cast(float, __builtin_amdgcn_readlane(__builtin_bit_cast(int, x), 63));
}
__device__ __forceinline__ int wimax_all(int x){
  const int ID = 0;
  x = max(x, idpp<0x111>(x, ID));
  x = max(x, idpp<0x112>(x, ID));
  x = max(x, idpp<0x114>(x, ID));
  x = max(x, idpp<0x118>(x, ID));
  x = max(x, idpp<0x142>(x, ID));
  x = max(x, idpp<0x143>(x, ID));
  return __builtin_amdgcn_readlane(x, 63);
}

// ---------------- prologue: G (f32 + f16), rpbc gather ----------------
__global__ void prologue_kernel(const float* __restrict__ Q, const float* __restrict__ Wq,
                                const float* __restrict__ Wk, const float* __restrict__ rpb,
                                const float* __restrict__ qc, const float* __restrict__ kc,
                                float* __restrict__ ws)
{
  __shared__ float Qp[384];
  const int tid = threadIdx.x;
  const int bid = blockIdx.x;
  float* G32 = ws;
  _Float16* G16 = (_Float16*)(ws + 1536);
  float* rpbc = ws + 2304;

  if (bid == 0){
    for (int i = tid; i < 384; i += 256){
      int m = i >> 5, d = i & 31;
      float a = 0.f;
      #pragma unroll
      for (int c = 0; c < 32; ++c) a += Q[m*32+c] * Wq[d*32+c];
      Qp[i] = a;
    }
    __syncthreads();
    const float s = 0.35355339059327373f; // 1/sqrt(8)
    for (int i = tid; i < 1536; i += 256){
      int hm = i >> 5, c = i & 31;
      int h = hm / 12, m = hm - 12*h;
      float a = 0.f;
      #pragma unroll
      for (int dh = 0; dh < 8; ++dh) a += Qp[m*32 + h*8 + dh] * Wk[(h*8+dh)*32 + c];
      G32[i] = a * s;
      G16[i] = (_Float16)(a * s);
    }
  }
  int i = bid*256 + tid;
  if (i < 9408){
    int hm = i / 196, n = i - 196*hm;
    int h = hm / 12, m = hm - 12*h;
    float dy = qc[2*m]   - kc[2*n];
    float dx = qc[2*m+1] - kc[2*n+1];
    int iy = (int)rintf(dy) + 13; iy = iy < 0 ? 0 : (iy > 26 ? 26 : iy);
    int ix = (int)rintf(dx) + 13; ix = ix < 0 ? 0 : (ix > 26 ? 26 : ix);
    rpbc[i] = rpb[h*729 + iy*27 + ix];
  }
}

// Ts16 chunk swizzle: row n, channel-chunk c8 (8 halfs) stored at chunk ((c8 + (n>>3)) & 3)
__device__ __forceinline__ int tsoff(int n, int c8){
  return n*40 + (((c8 + (n>>3)) & 3) << 3);
}

// ---------------- K1: content + softmax + entropy -> A (fp16, ws) ----------------
__global__ __launch_bounds__(256, 4) void k1_content(
    const float* __restrict__ T, const float* __restrict__ ws,
    _Float16* __restrict__ Aws, float* __restrict__ out)
{
  __shared__ __align__(16) _Float16 Ts16[196*40];

  const int b    = blockIdx.x;
  const int tid  = threadIdx.x;
  const int lane = tid & 63;
  const int h    = tid >> 6;

  const _Float16* G16 = (const _Float16*)(ws + 1536);
  const float* rpbc   = ws + 2304;
  float* outE = out + 9764864;

  // stage T -> fp16 LDS (chunk-swizzled)
  for (int i = tid; i < 784; i += 256){
    int n = i >> 2, c8 = i & 3;
    const float* src = T + (size_t)b*6272 + n*32 + c8*8;
    f32x4 v0 = *(const f32x4*)src;
    f32x4 v1 = *(const f32x4*)(src + 4);
    h8 hv;
    #pragma unroll
    for (int k = 0; k < 4; ++k){ hv[k] = (_Float16)v0[k]; hv[4+k] = (_Float16)v1[k]; }
    *(h8*)&Ts16[tsoff(n, c8)] = hv;
  }
  __syncthreads();

  const int n0 = lane, n1 = lane + 64, n2 = lane + 128, n3 = lane + 192;
  const bool v3 = (n3 < 196);
  const int n3c = v3 ? n3 : 195;

  float acc[12][4];
  #pragma unroll
  for (int m = 0; m < 12; ++m){
    const float* rrow = rpbc + (h*12 + m) * 196;
    acc[m][0] = rrow[n0]; acc[m][1] = rrow[n1];
    acc[m][2] = rrow[n2]; acc[m][3] = rrow[n3c];
  }
  #pragma unroll
  for (int c8 = 0; c8 < 4; ++c8){
    h8 t0 = *(const h8*)&Ts16[tsoff(n0,  c8)];
    h8 t1 = *(const h8*)&Ts16[tsoff(n1,  c8)];
    h8 t2 = *(const h8*)&Ts16[tsoff(n2,  c8)];
    h8 t3 = *(const h8*)&Ts16[tsoff(n3c, c8)];
    #pragma unroll
    for (int m = 0; m < 12; ++m){
      int gidx = __builtin_amdgcn_readfirstlane((h*12 + m)*32 + c8*8);
      h8 g = *(const h8*)(G16 + gidx);
      acc[m][0] = dot8h(t0, g, acc[m][0]);
      acc[m][1] = dot8h(t1, g, acc[m][1]);
      acc[m][2] = dot8h(t2, g, acc[m][2]);
      acc[m][3] = dot8h(t3, g, acc[m][3]);
    }
  }
  const float LOGN_INV = 0.18946127f; // 1/ln(196)
  #pragma unroll
  for (int m = 0; m < 12; ++m){
    float x0 = acc[m][0], x1 = acc[m][1], x2 = acc[m][2];
    float x3 = v3 ? acc[m][3] : -1e30f;
    float mx = wmax_all(fmaxf(fmaxf(x0, x1), fmaxf(x2, x3)));
    float e0 = __expf(x0 - mx), e1 = __expf(x1 - mx), e2 = __expf(x2 - mx);
    float e3 = v3 ? __expf(x3 - mx) : 0.f;
    float s  = wsum_all(e0 + e1 + e2 + e3);
    float t  = wsum_all((x0-mx)*e0 + (x1-mx)*e1 + (x2-mx)*e2 + (v3 ? (x3-mx)*e3 : 0.f));
    float inv = 1.f / s;
    _Float16* arow = Aws + ((size_t)b*48 + h*12 + m) * 200;
    arow[n0] = (_Float16)(e0 * inv);
    arow[n1] = (_Float16)(e1 * inv);
    arow[n2] = (_Float16)(e2 * inv);
    if (v3)            arow[n3] = (_Float16)(e3 * inv);
    else if (n3 < 200) arow[n3] = (_Float16)0.f;   // zero-pad n=196..199
    if (lane == 0)
      outE[(size_t)b*48 + m*4 + h] = 1.0f + (t*inv - __logf(s)) * LOGN_INV;
  }
}

// ---------------- K2a: A_avg, A_maps, top-9 mass. One wave per (b, m). ----------------
__global__ void k2a_topk(const _Float16* __restrict__ Aws, float* __restrict__ out)
{
  const int tid  = threadIdx.x;
  const int lane = tid & 63;
  const int w    = tid >> 6;
  const int bid  = blockIdx.x;          // 0..12287
  const int b    = bid / 3;
  const int m    = (bid % 3) * 4 + w;

  float* outA = out + 131072;
  float* outK = out + 11534336;

  const int n0 = lane, n1 = lane + 64, n2 = lane + 128, n3 = lane + 192;
  const bool v3 = (n3 < 196);
  const int n3c = v3 ? n3 : 195;

  const _Float16* base = Aws + ((size_t)b*48 + m) * 200;
  float a0 = 0.f, a1 = 0.f, a2 = 0.f, a3 = 0.f;
  #pragma unroll
  for (int h = 0; h < 4; ++h){
    const _Float16* r = base + h * 2400;
    a0 += (float)r[n0]; a1 += (float)r[n1];
    a2 += (float)r[n2]; a3 += (float)r[n3c];
  }
  float av0 = 0.25f*a0, av1 = 0.25f*a1, av2 = 0.25f*a2, av3 = 0.25f*a3;

  float* amrow = outA + (size_t)b*2352 + m*196;
  __builtin_nontemporal_store(av0, amrow + n0);
  __builtin_nontemporal_store(av1, amrow + n1);
  __builtin_nontemporal_store(av2, amrow + n2);
  if (v3) __builtin_nontemporal_store(av3, amrow + n3);

  int k0 = (__builtin_bit_cast(int, av0) & ~0xFF) | (lane << 2) | 0;
  int k1 = (__builtin_bit_cast(int, av1) & ~0xFF) | (lane << 2) | 1;
  int k2 = (__builtin_bit_cast(int, av2) & ~0xFF) | (lane << 2) | 2;
  int k3 = v3 ? ((__builtin_bit_cast(int, av3) & ~0xFF) | (lane << 2) | 3) : 0;

  float mass = 0.f;
  #pragma unroll
  for (int k = 0; k < 9; ++k){
    int g = wimax_all(max(max(k0, k1), max(k2, k3)));
    mass += __builtin_bit_cast(float, g & ~0xFF);
    int gl = (g >> 2) & 63, gq = g & 3;
    if (lane == gl){
      if      (gq == 0) k0 = 0;
      else if (gq == 1) k1 = 0;
      else if (gq == 2) k2 = 0;
      else              k3 = 0;
    }
  }
  if (lane == 0) __builtin_nontemporal_store(mass, outK + (size_t)b*12 + m);
}

// ---------------- K2b: U = A*T, S = U*Wv, Z = S*Wp + bp ----------------
__global__ __launch_bounds__(256, 4) void k2b_uv(
    const float* __restrict__ T, const float* __restrict__ Wv, const float* __restrict__ Wp,
    const float* __restrict__ bp, const _Float16* __restrict__ Aws, float* __restrict__ out)
{
  __shared__ __align__(16) _Float16 Al[48*200];   // A rows fp16
  __shared__ __align__(16) _Float16 Tt[32*200];   // T transposed [c][n] fp16
  __shared__ __align__(16) float U[48*32];
  __shared__ __align__(16) float Ss[384];
  __shared__ float red[256];

  const int b   = blockIdx.x;
  const int tid = threadIdx.x;

  float* outZ = out;
  float* outS = out + 9961472;

  // stage A (fp16, contiguous)
  const f32x4* Ab = (const f32x4*)(Aws + (size_t)b*9600);
  f32x4* Al4 = (f32x4*)Al;
  for (int i = tid; i < 1200; i += 256) Al4[i] = Ab[i];

  // stage T transposed -> fp16 (zero-pad n=196..199)
  const float* Tb = T + (size_t)b*6272;
  for (int i = tid; i < 6400; i += 256){
    int n = i >> 5, c = i & 31;
    float v = (n < 196) ? Tb[n*32 + c] : 0.f;
    Tt[c*200 + n] = (_Float16)v;
  }
  __syncthreads();

  // U: thread owns rows {mhg, mhg+16, mhg+32} x cols {2*cpair, 2*cpair+1}
  {
    const int cpair = tid >> 4;   // 0..15
    const int mhg   = tid & 15;   // 0..15
    float u00 = 0.f, u01 = 0.f, u10 = 0.f, u11 = 0.f, u20 = 0.f, u21 = 0.f;
    const h8* A0 = (const h8*)(Al + (size_t)mhg*200);
    const h8* A1 = (const h8*)(Al + (size_t)(mhg+16)*200);
    const h8* A2 = (const h8*)(Al + (size_t)(mhg+32)*200);
    const h8* T0 = (const h8*)(Tt + (size_t)(2*cpair)*200);
    const h8* T1 = (const h8*)(Tt + (size_t)(2*cpair+1)*200);
    #pragma unroll 5
    for (int n8 = 0; n8 < 25; ++n8){
      h8 a0 = A0[n8], a1 = A1[n8], a2 = A2[n8];
      h8 t0 = T0[n8], t1 = T1[n8];
      u00 = dot8h(a0, t0, u00); u01 = dot8h(a0, t1, u01);
      u10 = dot8h(a1, t0, u10); u11 = dot8h(a1, t1, u11);
      u20 = dot8h(a2, t0, u20); u21 = dot8h(a2, t1, u21);
    }
    float2* Up = (float2*)U;
    Up[(mhg     )*16 + cpair] = make_float2(u00, u01);
    Up[(mhg + 16)*16 + cpair] = make_float2(u10, u11);
    Up[(mhg + 32)*16 + cpair] = make_float2(u20, u21);
  }
  __syncthreads();

  // S[m][d] = sum_c U[(d>>3)*12+m][c] * Wv[d][c]
  for (int md = tid; md < 384; md += 256){
    int m = md >> 5, d = md & 31, hh = d >> 3;
    const float4* Urow = (const float4*)(U + (hh*12 + m)*32);
    const float4* Wvr  = (const float4*)(Wv + d*32);
    float a = 0.f;
    #pragma unroll
    for (int q = 0; q < 8; ++q) a += dot4(Urow[q], Wvr[q]);
    Ss[md] = a;
    __builtin_nontemporal_store(a, outS + (size_t)b*384 + md);
  }
  __syncthreads();

  // Z[d] = bp[d] + sum_j Wp[d][j] * Ss[j]
  {
    int d = tid >> 3, j4 = tid & 7;
    const float4* Wp4 = (const float4*)(Wp + d*384);
    const float4* Ss4 = (const float4*)Ss;
    float a = 0.f;
    #pragma unroll
    for (int jj = 0; jj < 12; ++jj){
      int j = j4 + jj*8;
      a += dot4(Wp4[j], Ss4[j]);
    }
    red[tid] = a;
  }
  __syncthreads();
  if (tid < 32){
    float a = bp[tid];
    #pragma unroll
    for (int k = 0; k < 8; ++k) a += red[tid*8 + k];
    __builtin_nontemporal_store(a, outZ + (size_t)b*32 + tid);
  }
}

// ---------------- fallback: round-2 single fused kernel (ws too small) ----------------
__global__ __launch_bounds__(256, 2) void slotpool_main(
    const float* __restrict__ T, const float* __restrict__ Wv, const float* __restrict__ Wp,
    const float* __restrict__ bp, const float* __restrict__ ws, float* __restrict__ out)
{
  __shared__ __align__(16) float Ts[196*36];
  __shared__ __align__(16) float As[48*196];
  __shared__ __align__(16) float GU[1536];
  __shared__ __align__(16) float Ss[384];
  __shared__ float red[256];

  const int b    = blockIdx.x;
  const int tid  = threadIdx.x;
  const int lane = tid & 63;
  const int h    = tid >> 6;

  float* outZ = out;
  float* outA = out + 131072;
  float* outE = out + 9764864;
  float* outS = out + 9961472;
  float* outK = out + 11534336;

  const float* G    = ws;
  const float* rpbc = ws + 2304;

  const f32x4* Tg = (const f32x4*)(T + (size_t)b * 6272);
  for (int i = tid; i < 1568; i += 256){
    int n = i >> 3, c4 = i & 7;
    f32x4 v = __builtin_nontemporal_load(Tg + i);
    *(f32x4*)&Ts[n*36 + c4*4] = v;
  }
  for (int i = tid; i < 384; i += 256) ((float4*)GU)[i] = ((const float4*)G)[i];
  __syncthreads();

  const int n0 = lane, n1 = lane + 64, n2 = lane + 128, n3 = lane + 192;
  const bool v3 = (n3 < 196);
  const int n3c = v3 ? n3 : 195;

  float acc[12][4];
  #pragma unroll
  for (int m = 0; m < 12; ++m){
    const float* rrow = rpbc + (h*12 + m) * 196;
    acc[m][0] = rrow[n0]; acc[m][1] = rrow[n1];
    acc[m][2] = rrow[n2]; acc[m][3] = rrow[n3c];
  }
  #pragma unroll
  for (int c4 = 0; c4 < 8; ++c4){
    float4 t0 = *(const float4*)&Ts[n0 *36 + c4*4];
    float4 t1 = *(const float4*)&Ts[n1 *36 + c4*4];
    float4 t2 = *(const float4*)&Ts[n2 *36 + c4*4];
    float4 t3 = *(const float4*)&Ts[n3c*36 + c4*4];
    #pragma unroll
    for (int m = 0; m < 12; ++m){
      float4 g = *(const float4*)&GU[(h*12 + m)*32 + c4*4];
      acc[m][0] += dot4(t0, g);
      acc[m][1] += dot4(t1, g);
      acc[m][2] += dot4(t2, g);
      acc[m][3] += dot4(t3, g);
    }
  }
  const float LOGN_INV = 0.18946127f;
  #pragma unroll
  for (int m = 0; m < 12; ++m){
    float x0 = acc[m][0], x1 = acc[m][1], x2 = acc[m][2];
    float x3 = v3 ? acc[m][3] : -1e30f;
    float mx = wmax_all(fmaxf(fmaxf(x0, x1), fmaxf(x2, x3)));
    float e0 = __expf(x0 - mx), e1 = __expf(x1 - mx), e2 = __expf(x2 - mx);
    float e3 = v3 ? __expf(x3 - mx) : 0.f;
    float s  = wsum_all(e0 + e1 + e2 + e3);
    float t  = wsum_all((x0-mx)*e0 + (x1-mx)*e1 + (x2-mx)*e2 + (v3 ? (x3-mx)*e3 : 0.f));
    float inv = 1.f / s;
    float* arow = As + (h*12 + m) * 196;
    arow[n0] = e0 * inv; arow[n1] = e1 * inv; arow[n2] = e2 * inv;
    if (v3) arow[n3] = e3 * inv;
    if (lane == 0)
      outE[(size_t)b*48 + m*4 + h] = 1.0f + (t*inv - __logf(s)) * LOGN_INV;
  }
  __syncthreads();

  #pragma unroll
  for (int mi = 0; mi < 3; ++mi){
    int m = h + mi*4;
    float av0 = 0.25f*(As[m*196+n0] + As[(12+m)*196+n0] + As[(24+m)*196+n0] + As[(36+m)*196+n0]);
    float av1 = 0.25f*(As[m*196+n1] + As[(12+m)*196+n1] + As[(24+m)*196+n1] + As[(36+m)*196+n1]);
    float av2 = 0.25f*(As[m*196+n2] + As[(12+m)*196+n2] + As[(24+m)*196+n2] + As[(36+m)*196+n2]);
    float av3 = 0.25f*(As[m*196+n3c] + As[(12+m)*196+n3c] + As[(24+m)*196+n3c] + As[(36+m)*196+n3c]);
    float* amrow = outA + (size_t)b*2352 + m*196;
    __builtin_nontemporal_store(av0, amrow + n0);
    __builtin_nontemporal_store(av1, amrow + n1);
    __builtin_nontemporal_store(av2, amrow + n2);
    if (v3) __builtin_nontemporal_store(av3, amrow + n3);

    int k0 = (__builtin_bit_cast(int, av0) & ~0xFF) | (lane << 2) | 0;
    int k1 = (__builtin_bit_cast(int, av1) & ~0xFF) | (lane << 2) | 1;
    int k2 = (__builtin_bit_cast(int, av2) & ~0xFF) | (lane << 2) | 2;
    int k3 = v3 ? ((__builtin_bit_cast(int, av3) & ~0xFF) | (lane << 2) | 3) : 0;

    float mass = 0.f;
    #pragma unroll
    for (int k = 0; k < 9; ++k){
      int g = wimax_all(max(max(k0, k1), max(k2, k3)));
      mass += __builtin_bit_cast(float, g & ~0xFF);
      int gl = (g >> 2) & 63, gq = g & 3;
      if (lane == gl){
        if      (gq == 0) k0 = 0;
        else if (gq == 1) k1 = 0;
        else if (gq == 2) k2 = 0;
        else              k3 = 0;
      }
    }
    if (lane == 0) __builtin_nontemporal_store(mass, outK + (size_t)b*12 + m);
  }

  {
    const int c4  = tid & 7;
    const int mh0 = tid >> 3;
    #pragma unroll
    for (int k = 0; k < 2; ++k){
      int mh = mh0 + 32*k;
      if (mh < 48){
        const float4* Arow = (const float4*)(As + mh*196);
        float4 u = {0.f, 0.f, 0.f, 0.f};
        for (int q = 0; q < 49; ++q){
          float4 a = Arow[q];
          const float* tb = &Ts[(4*q)*36 + c4*4];
          float4 p0 = *(const float4*)(tb);
          float4 p1 = *(const float4*)(tb + 36);
          float4 p2 = *(const float4*)(tb + 72);
          float4 p3 = *(const float4*)(tb + 108);
          u.x += a.x*p0.x + a.y*p1.x + a.z*p2.x + a.w*p3.x;
          u.y += a.x*p0.y + a.y*p1.y + a.z*p2.y + a.w*p3.y;
          u.z += a.x*p0.z + a.y*p1.z + a.z*p2.z + a.w*p3.z;
          u.w += a.x*p0.w + a.y*p1.w + a.z*p2.w + a.w*p3.w;
        }
        *(float4*)&GU[mh*32 + c4*4] = u;
      }
    }
  }
  __syncthreads();

  for (int md = tid; md < 384; md += 256){
    int m = md >> 5, d = md & 31, hh = d >> 3;
    const float4* Urow = (const float4*)(GU + (hh*12 + m)*32);
    const float4* Wvr  = (const float4*)(Wv + d*32);
    float a = 0.f;
    #pragma unroll
    for (int q = 0; q < 8; ++q) a += dot4(Urow[q], Wvr[q]);
    Ss[md] = a;
    __builtin_nontemporal_store(a, outS + (size_t)b*384 + md);
  }
  __syncthreads();

  {
    int d = tid >> 3, j4 = tid & 7;
    const float4* Wp4 = (const float4*)(Wp + d*384);
    const float4* Ss4 = (const float4*)Ss;
    float a = 0.f;
    #pragma unroll
    for (int jj = 0; jj < 12; ++jj){
      int j = j4 + jj*8;
      a += dot4(Wp4[j], Ss4[j]);
    }
    red[tid] = a;
  }
  __syncthreads();
  if (tid < 32){
    float a = bp[tid];
    #pragma unroll
    for (int k = 0; k < 8; ++k) a += red[tid*8 + k];
    __builtin_nontemporal_store(a, outZ + (size_t)b*32 + tid);
  }
}

extern "C" void kernel_launch(void* const* d_in, const int* in_sizes, int n_in,
                              void* d_out, int out_size, void* d_ws, size_t ws_size,
                              hipStream_t stream)
{
  const float* T    = (const float*)d_in[0];
  const float* Q    = (const float*)d_in[1];
  const float* Wq   = (const float*)d_in[2];
  const float* Wk   = (const float*)d_in[3];
  const float* Wv   = (const float*)d_in[4];
  const float* Wp   = (const float*)d_in[5];
  const float* bp   = (const float*)d_in[6];
  const float* rpb  = (const float*)d_in[7];
  const float* qc   = (const float*)d_in[8];
  const float* kc   = (const float*)d_in[9];
  float* ws   = (float*)d_ws;
  float* outp = (float*)d_out;

  prologue_kernel<<<40, 256, 0, stream>>>(Q, Wq, Wk, rpb, qc, kc, ws);

  const size_t NEEDED = 49152ull + 4096ull*48*200*2;  // 78,692,352 B
  if (ws_size >= NEEDED){
    _Float16* Aws = (_Float16*)((char*)d_ws + 49152);
    k1_content<<<4096, 256, 0, stream>>>(T, ws, Aws, outp);
    k2b_uv<<<4096, 256, 0, stream>>>(T, Wv, Wp, bp, Aws, outp);
    k2a_topk<<<12288, 256, 0, stream>>>(Aws, outp);
  } else {
    slotpool_main<<<4096, 256, 0, stream>>>(T, Wv, Wp, bp, ws, outp);
  }
}

// Round 4
// 144.355 us; speedup vs baseline: 6.3494x; 1.2947x over previous
//
#include <hip/hip_runtime.h>
#include <math.h>

// B=4096, N=196, D=32, M=12, NH=4, DH=8, H=W=14
// outputs (flat f32): Z[4096*32] | A_maps[4096*12*196] | head_energy[4096*12*4] | S[4096*12*32] | topk_mass[4096*12]
// ws layout: G32[1536 f32] @0 | G16[1536 f16] @ float-off 1536 | rpbc[9408 f32] @ float-off 2304

typedef float f32x4 __attribute__((ext_vector_type(4)));
typedef _Float16 h2 __attribute__((ext_vector_type(2)));
typedef _Float16 h8 __attribute__((ext_vector_type(8)));

__device__ __forceinline__ float dot4(float4 a, float4 b){
  return a.x*b.x + a.y*b.y + a.z*b.z + a.w*b.w;
}

#define H2S(v,k) __builtin_shufflevector((v), (v), 2*(k), 2*(k)+1)

#if __has_builtin(__builtin_amdgcn_fdot2)
__device__ __forceinline__ float FDOT2(h2 a, h2 b, float c){
  return __builtin_amdgcn_fdot2(a, b, c, false);
}
#else
__device__ __forceinline__ float FDOT2(h2 a, h2 b, float c){
  return c + (float)a[0]*(float)b[0] + (float)a[1]*(float)b[1];
}
#endif

__device__ __forceinline__ float dot8h(h8 a, h8 b, float c){
  c = FDOT2(H2S(a,0), H2S(b,0), c);
  c = FDOT2(H2S(a,1), H2S(b,1), c);
  c = FDOT2(H2S(a,2), H2S(b,2), c);
  c = FDOT2(H2S(a,3), H2S(b,3), c);
  return c;
}

// ---- DPP-based wave64 reductions (VALU pipe, no LDS) ----
template<int CTRL>
__device__ __forceinline__ float fdpp(float x, float id){
  return __builtin_bit_cast(float,
    __builtin_amdgcn_update_dpp(__builtin_bit_cast(int, id),
                                __builtin_bit_cast(int, x),
                                CTRL, 0xF, 0xF, false));
}
template<int CTRL>
__device__ __forceinline__ int idpp(int x, int id){
  return __builtin_amdgcn_update_dpp(id, x, CTRL, 0xF, 0xF, false);
}
__device__ __forceinline__ float wmax_all(float x){
  const float ID = -1e30f;
  x = fmaxf(x, fdpp<0x111>(x, ID));
  x = fmaxf(x, fdpp<0x112>(x, ID));
  x = fmaxf(x, fdpp<0x114>(x, ID));
  x = fmaxf(x, fdpp<0x118>(x, ID));
  x = fmaxf(x, fdpp<0x142>(x, ID));
  x = fmaxf(x, fdpp<0x143>(x, ID));
  return __builtin_bit_cast(float, __builtin_amdgcn_readlane(__builtin_bit_cast(int, x), 63));
}
__device__ __forceinline__ float wsum_all(float x){
  x += fdpp<0x111>(x, 0.f);
  x += fdpp<0x112>(x, 0.f);
  x += fdpp<0x114>(x, 0.f);
  x += fdpp<0x118>(x, 0.f);
  x += fdpp<0x142>(x, 0.f);
  x += fdpp<0x143>(x, 0.f);
  return __builtin_bit_cast(float, __builtin_amdgcn_readlane(__builtin_bit_cast(int, x), 63));
}
__device__ __forceinline__ int wimax_all(int x){
  const int ID = 0;
  x = max(x, idpp<0x111>(x, ID));
  x = max(x, idpp<0x112>(x, ID));
  x = max(x, idpp<0x114>(x, ID));
  x = max(x, idpp<0x118>(x, ID));
  x = max(x, idpp<0x142>(x, ID));
  x = max(x, idpp<0x143>(x, ID));
  return __builtin_amdgcn_readlane(x, 63);
}

// ---------------- prologue: G (f32 + f16), rpbc gather ----------------
__global__ void prologue_kernel(const float* __restrict__ Q, const float* __restrict__ Wq,
                                const float* __restrict__ Wk, const float* __restrict__ rpb,
                                const float* __restrict__ qc, const float* __restrict__ kc,
                                float* __restrict__ ws)
{
  __shared__ float Qp[384];
  const int tid = threadIdx.x;
  const int bid = blockIdx.x;
  float* G32 = ws;
  _Float16* G16 = (_Float16*)(ws + 1536);
  float* rpbc = ws + 2304;

  if (bid == 0){
    for (int i = tid; i < 384; i += 256){
      int m = i >> 5, d = i & 31;
      float a = 0.f;
      #pragma unroll
      for (int c = 0; c < 32; ++c) a += Q[m*32+c] * Wq[d*32+c];
      Qp[i] = a;
    }
    __syncthreads();
    const float s = 0.35355339059327373f; // 1/sqrt(8)
    for (int i = tid; i < 1536; i += 256){
      int hm = i >> 5, c = i & 31;
      int h = hm / 12, m = hm - 12*h;
      float a = 0.f;
      #pragma unroll
      for (int dh = 0; dh < 8; ++dh) a += Qp[m*32 + h*8 + dh] * Wk[(h*8+dh)*32 + c];
      G32[i] = a * s;
      G16[i] = (_Float16)(a * s);
    }
  }
  int i = bid*256 + tid;
  if (i < 9408){
    int hm = i / 196, n = i - 196*hm;
    int h = hm / 12, m = hm - 12*h;
    float dy = qc[2*m]   - kc[2*n];
    float dx = qc[2*m+1] - kc[2*n+1];
    int iy = (int)rintf(dy) + 13; iy = iy < 0 ? 0 : (iy > 26 ? 26 : iy);
    int ix = (int)rintf(dx) + 13; ix = ix < 0 ? 0 : (ix > 26 ? 26 : ix);
    rpbc[i] = rpb[h*729 + iy*27 + ix];
  }
}

// Ts16 chunk swizzle: row n, channel-chunk c8 (8 halfs) stored at chunk ((c8 + (n>>3)) & 3)
__device__ __forceinline__ int tsoff(int n, int c8){
  return n*40 + (((c8 + (n>>3)) & 3) << 3);
}

// ---------------- fully fused kernel: one block per batch element ----------------
__global__ __launch_bounds__(256, 3) void fused_main(
    const float* __restrict__ T, const float* __restrict__ Wv, const float* __restrict__ Wp,
    const float* __restrict__ bp, const float* __restrict__ ws, float* __restrict__ out)
{
  // TsBuf: first holds Ts16 [196][40] swizzled row-major (15680 B),
  // later re-used (aliased) as Tt16 [32][200] transposed (12800 B).
  __shared__ __align__(16) _Float16 TsBuf[196*40];
  __shared__ __align__(16) _Float16 As[48*200];    // A fp16, rows padded to 200 (zeros 196..199)
  __shared__ __align__(16) float U[48*32];
  __shared__ __align__(16) float Ss[384];
  __shared__ float red[256];

  const int b    = blockIdx.x;
  const int tid  = threadIdx.x;
  const int lane = tid & 63;
  const int h    = tid >> 6;   // wave id == head in phase B

  float* outZ = out;                       // [4096][32]
  float* outA = out + 131072;              // [4096][12][196]
  float* outE = out + 9764864;             // [4096][12][4]
  float* outS = out + 9961472;             // [4096][12][32]
  float* outK = out + 11534336;            // [4096][12]

  const _Float16* G16 = (const _Float16*)(ws + 1536);
  const float* rpbc   = ws + 2304;

  // ---- A: stage T -> fp16 LDS (chunk-swizzled) ----
  for (int i = tid; i < 784; i += 256){
    int n = i >> 2, c8 = i & 3;
    const float* src = T + (size_t)b*6272 + n*32 + c8*8;
    f32x4 v0 = *(const f32x4*)src;
    f32x4 v1 = *(const f32x4*)(src + 4);
    h8 hv;
    #pragma unroll
    for (int k = 0; k < 4; ++k){ hv[k] = (_Float16)v0[k]; hv[4+k] = (_Float16)v1[k]; }
    *(h8*)&TsBuf[tsoff(n, c8)] = hv;
  }
  __syncthreads();

  // ---- B: content (T @ G^T) + rpb, softmax over n, entropy; A -> LDS fp16 ----
  const int n0 = lane, n1 = lane + 64, n2 = lane + 128, n3 = lane + 192;
  const bool v3 = (n3 < 196);
  const int n3c = v3 ? n3 : 195;

  {
    float acc[12][4];
    #pragma unroll
    for (int m = 0; m < 12; ++m){
      const float* rrow = rpbc + (h*12 + m) * 196;
      acc[m][0] = rrow[n0]; acc[m][1] = rrow[n1];
      acc[m][2] = rrow[n2]; acc[m][3] = rrow[n3c];
    }
    #pragma unroll
    for (int c8 = 0; c8 < 4; ++c8){
      h8 t0 = *(const h8*)&TsBuf[tsoff(n0,  c8)];
      h8 t1 = *(const h8*)&TsBuf[tsoff(n1,  c8)];
      h8 t2 = *(const h8*)&TsBuf[tsoff(n2,  c8)];
      h8 t3 = *(const h8*)&TsBuf[tsoff(n3c, c8)];
      #pragma unroll
      for (int m = 0; m < 12; ++m){
        int gidx = __builtin_amdgcn_readfirstlane((h*12 + m)*32 + c8*8);
        h8 g = *(const h8*)(G16 + gidx);
        acc[m][0] = dot8h(t0, g, acc[m][0]);
        acc[m][1] = dot8h(t1, g, acc[m][1]);
        acc[m][2] = dot8h(t2, g, acc[m][2]);
        acc[m][3] = dot8h(t3, g, acc[m][3]);
      }
    }
    const float LOGN_INV = 0.18946127f; // 1/ln(196)
    #pragma unroll
    for (int m = 0; m < 12; ++m){
      float x0 = acc[m][0], x1 = acc[m][1], x2 = acc[m][2];
      float x3 = v3 ? acc[m][3] : -1e30f;
      float mx = wmax_all(fmaxf(fmaxf(x0, x1), fmaxf(x2, x3)));
      float e0 = __expf(x0 - mx), e1 = __expf(x1 - mx), e2 = __expf(x2 - mx);
      float e3 = v3 ? __expf(x3 - mx) : 0.f;
      float s  = wsum_all(e0 + e1 + e2 + e3);
      float t  = wsum_all((x0-mx)*e0 + (x1-mx)*e1 + (x2-mx)*e2 + (v3 ? (x3-mx)*e3 : 0.f));
      float inv = 1.f / s;
      _Float16* arow = As + (h*12 + m) * 200;
      arow[n0] = (_Float16)(e0 * inv);
      arow[n1] = (_Float16)(e1 * inv);
      arow[n2] = (_Float16)(e2 * inv);
      if (v3)            arow[n3] = (_Float16)(e3 * inv);
      else if (n3 < 200) arow[n3] = (_Float16)0.f;   // zero-pad 196..199
      if (lane == 0)
        outE[(size_t)b*48 + m*4 + h] = 1.0f + (t*inv - __logf(s)) * LOGN_INV;
    }
  }
  __syncthreads();

  // ---- D-read: pull transpose chunks of Ts16 into registers (write after topk) ----
  h8 tr0, tr1, tr2, tr3;
  {
    int j0 = tid, j1 = tid + 256, j2 = tid + 512;
    tr0 = *(const h8*)&TsBuf[tsoff(j0 >> 2, j0 & 3)];
    tr1 = *(const h8*)&TsBuf[tsoff(j1 >> 2, j1 & 3)];
    tr2 = *(const h8*)&TsBuf[tsoff(j2 >> 2, j2 & 3)];
    if (tid < 16){
      int j3 = tid + 768;
      tr3 = *(const h8*)&TsBuf[tsoff(j3 >> 2, j3 & 3)];
    }
  }

  // ---- C: A_avg over heads, A_maps out, top-9 mass (packed int-key argmax) ----
  #pragma unroll
  for (int mi = 0; mi < 3; ++mi){
    int m = h + mi*4;
    float av0 = 0.25f*((float)As[m*200+n0] + (float)As[(12+m)*200+n0] + (float)As[(24+m)*200+n0] + (float)As[(36+m)*200+n0]);
    float av1 = 0.25f*((float)As[m*200+n1] + (float)As[(12+m)*200+n1] + (float)As[(24+m)*200+n1] + (float)As[(36+m)*200+n1]);
    float av2 = 0.25f*((float)As[m*200+n2] + (float)As[(12+m)*200+n2] + (float)As[(24+m)*200+n2] + (float)As[(36+m)*200+n2]);
    float av3 = 0.25f*((float)As[m*200+n3c] + (float)As[(12+m)*200+n3c] + (float)As[(24+m)*200+n3c] + (float)As[(36+m)*200+n3c]);
    float* amrow = outA + (size_t)b*2352 + m*196;
    __builtin_nontemporal_store(av0, amrow + n0);
    __builtin_nontemporal_store(av1, amrow + n1);
    __builtin_nontemporal_store(av2, amrow + n2);
    if (v3) __builtin_nontemporal_store(av3, amrow + n3);

    int k0 = (__builtin_bit_cast(int, av0) & ~0xFF) | (lane << 2) | 0;
    int k1 = (__builtin_bit_cast(int, av1) & ~0xFF) | (lane << 2) | 1;
    int k2 = (__builtin_bit_cast(int, av2) & ~0xFF) | (lane << 2) | 2;
    int k3 = v3 ? ((__builtin_bit_cast(int, av3) & ~0xFF) | (lane << 2) | 3) : 0;

    float mass = 0.f;
    #pragma unroll
    for (int k = 0; k < 9; ++k){
      int g = wimax_all(max(max(k0, k1), max(k2, k3)));
      mass += __builtin_bit_cast(float, g & ~0xFF);
      int gl = (g >> 2) & 63, gq = g & 3;
      if (lane == gl){
        if      (gq == 0) k0 = 0;
        else if (gq == 1) k1 = 0;
        else if (gq == 2) k2 = 0;
        else              k3 = 0;
      }
    }
    if (lane == 0) __builtin_nontemporal_store(mass, outK + (size_t)b*12 + m);
  }
  __syncthreads();   // all transpose-reads done; safe to overwrite TsBuf

  // ---- D-write: Tt16[c][n] = T[n][c] (aliased over TsBuf), zero-pad n=196..199 ----
  {
    _Float16* Tt = TsBuf;
    int j0 = tid, j1 = tid + 256, j2 = tid + 512;
    int n, c8;
    n = j0 >> 2; c8 = j0 & 3;
    #pragma unroll
    for (int k = 0; k < 8; ++k) Tt[(c8*8 + k)*200 + n] = tr0[k];
    n = j1 >> 2; c8 = j1 & 3;
    #pragma unroll
    for (int k = 0; k < 8; ++k) Tt[(c8*8 + k)*200 + n] = tr1[k];
    n = j2 >> 2; c8 = j2 & 3;
    #pragma unroll
    for (int k = 0; k < 8; ++k) Tt[(c8*8 + k)*200 + n] = tr2[k];
    if (tid < 16){
      int j3 = tid + 768;
      n = j3 >> 2; c8 = j3 & 3;
      #pragma unroll
      for (int k = 0; k < 8; ++k) Tt[(c8*8 + k)*200 + n] = tr3[k];
    }
    if (tid < 128){
      int c = tid >> 2, nn = 196 + (tid & 3);
      Tt[c*200 + nn] = (_Float16)0.f;
    }
  }
  __syncthreads();

  // ---- E: U[mh][c] = sum_n A[mh][n] * T[n][c]  via dot2 on fp16 ----
  {
    const _Float16* Tt = TsBuf;
    const int cpair = tid >> 4;   // 0..15
    const int mhg   = tid & 15;   // 0..15
    float u00 = 0.f, u01 = 0.f, u10 = 0.f, u11 = 0.f, u20 = 0.f, u21 = 0.f;
    const h8* A0 = (const h8*)(As + (size_t)mhg*200);
    const h8* A1 = (const h8*)(As + (size_t)(mhg+16)*200);
    const h8* A2 = (const h8*)(As + (size_t)(mhg+32)*200);
    const h8* T0 = (const h8*)(Tt + (size_t)(2*cpair)*200);
    const h8* T1 = (const h8*)(Tt + (size_t)(2*cpair+1)*200);
    #pragma unroll 5
    for (int n8 = 0; n8 < 25; ++n8){
      h8 a0 = A0[n8], a1 = A1[n8], a2 = A2[n8];
      h8 t0 = T0[n8], t1 = T1[n8];
      u00 = dot8h(a0, t0, u00); u01 = dot8h(a0, t1, u01);
      u10 = dot8h(a1, t0, u10); u11 = dot8h(a1, t1, u11);
      u20 = dot8h(a2, t0, u20); u21 = dot8h(a2, t1, u21);
    }
    float2* Up = (float2*)U;
    Up[(mhg     )*16 + cpair] = make_float2(u00, u01);
    Up[(mhg + 16)*16 + cpair] = make_float2(u10, u11);
    Up[(mhg + 32)*16 + cpair] = make_float2(u20, u21);
  }
  __syncthreads();

  // ---- S: S[m][d] = sum_c U[(d>>3)*12+m][c] * Wv[d][c]; write S out ----
  for (int md = tid; md < 384; md += 256){
    int m = md >> 5, d = md & 31, hh = d >> 3;
    const float4* Urow = (const float4*)(U + (hh*12 + m)*32);
    const float4* Wvr  = (const float4*)(Wv + d*32);
    float a = 0.f;
    #pragma unroll
    for (int q = 0; q < 8; ++q) a += dot4(Urow[q], Wvr[q]);
    Ss[md] = a;
    __builtin_nontemporal_store(a, outS + (size_t)b*384 + md);
  }
  __syncthreads();

  // ---- Z: Z[d] = bp[d] + sum_j Wp[d][j] * Ss[j] ----
  {
    int d = tid >> 3, j4 = tid & 7;
    const float4* Wp4 = (const float4*)(Wp + d*384);
    const float4* Ss4 = (const float4*)Ss;
    float a = 0.f;
    #pragma unroll
    for (int jj = 0; jj < 12; ++jj){
      int j = j4 + jj*8;
      a += dot4(Wp4[j], Ss4[j]);
    }
    red[tid] = a;
  }
  __syncthreads();
  if (tid < 32){
    float a = bp[tid];
    #pragma unroll
    for (int k = 0; k < 8; ++k) a += red[tid*8 + k];
    __builtin_nontemporal_store(a, outZ + (size_t)b*32 + tid);
  }
}

extern "C" void kernel_launch(void* const* d_in, const int* in_sizes, int n_in,
                              void* d_out, int out_size, void* d_ws, size_t ws_size,
                              hipStream_t stream)
{
  const float* T    = (const float*)d_in[0];
  const float* Q    = (const float*)d_in[1];
  const float* Wq   = (const float*)d_in[2];
  const float* Wk   = (const float*)d_in[3];
  const float* Wv   = (const float*)d_in[4];
  const float* Wp   = (const float*)d_in[5];
  const float* bp   = (const float*)d_in[6];
  const float* rpb  = (const float*)d_in[7];
  const float* qc   = (const float*)d_in[8];
  const float* kc   = (const float*)d_in[9];
  float* ws   = (float*)d_ws;
  float* outp = (float*)d_out;

  prologue_kernel<<<40, 256, 0, stream>>>(Q, Wq, Wk, rpb, qc, kc, ws);
  fused_main<<<4096, 256, 0, stream>>>(T, Wv, Wp, bp, ws, outp);
}

// Round 5
// 86.870 us; speedup vs baseline: 10.5510x; 1.6617x over previous
//
#include <hip/hip_runtime.h>
#include <math.h>

// B=4096, N=196, D=32, M=12, NH=4, DH=8, H=W=14
// outputs (flat f32): Z[4096*32] | A_maps[4096*12*196] | head_energy[4096*12*4] | S[4096*12*32] | topk_mass[4096*12]
// ws layout (bytes): G16 fp16[48*32] @0 | rpbc16 fp16[48*208] @4096  (pad cols 196..207 = -60000)

typedef float f32x4 __attribute__((ext_vector_type(4)));
typedef _Float16 h4 __attribute__((ext_vector_type(4)));
typedef _Float16 h8 __attribute__((ext_vector_type(8)));

__device__ __forceinline__ float dot4(float4 a, float4 b){
  return a.x*b.x + a.y*b.y + a.z*b.z + a.w*b.w;
}

// ---- DPP int-max reduction (topk) ----
template<int CTRL>
__device__ __forceinline__ int idpp(int x, int id){
  return __builtin_amdgcn_update_dpp(id, x, CTRL, 0xF, 0xF, false);
}
__device__ __forceinline__ int wimax_all(int x){
  const int ID = 0;
  x = max(x, idpp<0x111>(x, ID));
  x = max(x, idpp<0x112>(x, ID));
  x = max(x, idpp<0x114>(x, ID));
  x = max(x, idpp<0x118>(x, ID));
  x = max(x, idpp<0x142>(x, ID));
  x = max(x, idpp<0x143>(x, ID));
  return __builtin_amdgcn_readlane(x, 63);
}

// ---------------- prologue: G16 = (Q Wq^T sliced)·Wk/sqrt(8) fp16; rpbc16 padded ----------------
__global__ void prologue_kernel(const float* __restrict__ Q, const float* __restrict__ Wq,
                                const float* __restrict__ Wk, const float* __restrict__ rpb,
                                const float* __restrict__ qc, const float* __restrict__ kc,
                                _Float16* __restrict__ G16, _Float16* __restrict__ rpbc16)
{
  __shared__ float Qp[384];
  const int tid = threadIdx.x;
  const int bid = blockIdx.x;

  if (bid == 0){
    for (int i = tid; i < 384; i += 256){
      int m = i >> 5, d = i & 31;
      float a = 0.f;
      #pragma unroll
      for (int c = 0; c < 32; ++c) a += Q[m*32+c] * Wq[d*32+c];
      Qp[i] = a;
    }
    __syncthreads();
    const float s = 0.35355339059327373f; // 1/sqrt(8)
    for (int i = tid; i < 1536; i += 256){
      int hm = i >> 5, c = i & 31;
      int hh = hm / 12, mm = hm - 12*hh;
      float a = 0.f;
      #pragma unroll
      for (int dh = 0; dh < 8; ++dh) a += Qp[mm*32 + hh*8 + dh] * Wk[(hh*8+dh)*32 + c];
      G16[i] = (_Float16)(a * s);
    }
  }
  int i = bid*256 + tid;
  if (i < 9984){                       // 48 rows x 208 cols
    int mh = i / 208, n = i - mh*208;
    float v;
    if (n < 196){
      int hh = mh / 12, mm = mh - 12*hh;
      float dy = qc[2*mm]   - kc[2*n];
      float dx = qc[2*mm+1] - kc[2*n+1];
      int iy = (int)rintf(dy) + 13; iy = iy < 0 ? 0 : (iy > 26 ? 26 : iy);
      int ix = (int)rintf(dx) + 13; ix = ix < 0 ? 0 : (ix > 26 ? 26 : ix);
      v = rpb[hh*729 + iy*27 + ix];
    } else {
      v = -60000.0f;                   // pad: exp -> 0, never the max
    }
    rpbc16[i] = (_Float16)v;
  }
}

// Ts16 chunk swizzle: row n, chunk c8 (8 halfs) stored at chunk ((c8 + (n>>3)) & 3)
__device__ __forceinline__ int tsoff(int n, int c8){
  return n*40 + (((c8 + (n>>3)) & 3) << 3);
}

// ---------------- fully fused kernel: one block per batch element ----------------
__global__ __launch_bounds__(256, 3) void fused_main(
    const float* __restrict__ T, const float* __restrict__ Wv, const float* __restrict__ Wp,
    const float* __restrict__ bp, const _Float16* __restrict__ G16,
    const _Float16* __restrict__ rpbc16, float* __restrict__ out)
{
  __shared__ __align__(16) _Float16 Ts16[224*40];   // T fp16, rows 196..223 zero, chunk-swizzled
  __shared__ __align__(16) _Float16 As[48*232];     // A fp16, cols 196..223 zero (196..207 via exp=0)
  __shared__ __align__(16) float U[48*36];          // U[mh][c], stride 36
  __shared__ __align__(16) float Ss[384];
  __shared__ float red[256];

  const int b    = blockIdx.x;
  const int tid  = threadIdx.x;
  const int lane = tid & 63;
  const int h    = tid >> 6;       // wave id
  const int r15  = lane & 15;
  const int g    = lane >> 4;

  float* outZ = out;                       // [4096][32]
  float* outA = out + 131072;              // [4096][12][196]
  float* outE = out + 9764864;             // [4096][12][4]
  float* outS = out + 9961472;             // [4096][12][32]
  float* outK = out + 11534336;            // [4096][12]

  // ---- A: stage T -> fp16 LDS (chunk-swizzled), zero rows 196..223 ----
  for (int i = tid; i < 896; i += 256){
    int n = i >> 2, c8 = i & 3;
    h8 hv = {0,0,0,0,0,0,0,0};
    if (n < 196){
      const f32x4* src = (const f32x4*)(T + (size_t)b*6272 + n*32 + c8*8);
      f32x4 v0 = __builtin_nontemporal_load(src);
      f32x4 v1 = __builtin_nontemporal_load(src + 1);
      #pragma unroll
      for (int k = 0; k < 4; ++k){ hv[k] = (_Float16)v0[k]; hv[4+k] = (_Float16)v1[k]; }
    }
    *(h8*)&Ts16[tsoff(n, c8)] = hv;
  }
  // zero As cols [208,224) (cols 196..207 get exact zeros from the exp write)
  if (tid < 96){
    int row = tid >> 1, part = tid & 1;
    h8 z = {0,0,0,0,0,0,0,0};
    *(h8*)&As[row*232 + 208 + part*8] = z;
  }

  // B-frag (G row) + rpb accumulator init: issue global loads before the barrier
  const int mhB = h*12 + (r15 < 12 ? r15 : 11);   // clamp lanes 12..15 (outputs discarded)
  h8 bfrag = *(const h8*)(G16 + mhB*32 + g*8);
  f32x4 acc[13];
  #pragma unroll
  for (int t = 0; t < 13; ++t){
    h4 rp = *(const h4*)(rpbc16 + mhB*208 + t*16 + g*4);
    acc[t][0] = (float)rp[0]; acc[t][1] = (float)rp[1];
    acc[t][2] = (float)rp[2]; acc[t][3] = (float)rp[3];
  }
  __syncthreads();

  // ---- B: content via MFMA.  C[n][mh]: n = t*16 + g*4 + r, mh col = r15. ----
  #pragma unroll
  for (int t = 0; t < 13; ++t){
    h8 af = *(const h8*)&Ts16[tsoff(t*16 + r15, g)];   // A row = r15, k-chunk = g
    acc[t] = __builtin_amdgcn_mfma_f32_16x16x32_f16(af, bfrag, acc[t], 0, 0, 0);
  }

  // per-lane softmax over the 52 n-values + cross-lane combine (lanes sharing r15)
  float mx = -1e30f;
  #pragma unroll
  for (int t = 0; t < 13; ++t)
    mx = fmaxf(mx, fmaxf(fmaxf(acc[t][0], acc[t][1]), fmaxf(acc[t][2], acc[t][3])));
  mx = fmaxf(mx, __shfl_xor(mx, 16));
  mx = fmaxf(mx, __shfl_xor(mx, 32));
  float se = 0.f, te = 0.f;
  #pragma unroll
  for (int t = 0; t < 13; ++t){
    #pragma unroll
    for (int r = 0; r < 4; ++r){
      float d = acc[t][r] - mx;
      float e = __expf(d);
      se += e; te += d*e;
      acc[t][r] = e;
    }
  }
  se += __shfl_xor(se, 16); se += __shfl_xor(se, 32);
  te += __shfl_xor(te, 16); te += __shfl_xor(te, 32);
  const float inv = 1.f / se;
  if (r15 < 12){
    #pragma unroll
    for (int t = 0; t < 13; ++t){
      h4 w4;
      w4[0] = (_Float16)(acc[t][0]*inv); w4[1] = (_Float16)(acc[t][1]*inv);
      w4[2] = (_Float16)(acc[t][2]*inv); w4[3] = (_Float16)(acc[t][3]*inv);
      *(h4*)&As[mhB*232 + t*16 + g*4] = w4;
    }
    if (g == 0){
      const float LOGN_INV = 0.18946127f; // 1/ln(196)
      outE[(size_t)b*48 + r15*4 + h] = 1.0f + (te*inv - __logf(se)) * LOGN_INV;
    }
  }
  __syncthreads();

  // ---- C: A_avg over heads, A_maps out, top-9 mass (packed int-key argmax) ----
  const int n0 = lane, n1 = lane + 64, n2 = lane + 128, n3 = lane + 192;
  const bool v3 = (n3 < 196);
  const int n3c = v3 ? n3 : 195;
  #pragma unroll
  for (int mi = 0; mi < 3; ++mi){
    int m = h + mi*4;
    float av0 = 0.25f*((float)As[m*232+n0] + (float)As[(12+m)*232+n0] + (float)As[(24+m)*232+n0] + (float)As[(36+m)*232+n0]);
    float av1 = 0.25f*((float)As[m*232+n1] + (float)As[(12+m)*232+n1] + (float)As[(24+m)*232+n1] + (float)As[(36+m)*232+n1]);
    float av2 = 0.25f*((float)As[m*232+n2] + (float)As[(12+m)*232+n2] + (float)As[(24+m)*232+n2] + (float)As[(36+m)*232+n2]);
    float av3 = 0.25f*((float)As[m*232+n3c] + (float)As[(12+m)*232+n3c] + (float)As[(24+m)*232+n3c] + (float)As[(36+m)*232+n3c]);
    float* amrow = outA + (size_t)b*2352 + m*196;
    __builtin_nontemporal_store(av0, amrow + n0);
    __builtin_nontemporal_store(av1, amrow + n1);
    __builtin_nontemporal_store(av2, amrow + n2);
    if (v3) __builtin_nontemporal_store(av3, amrow + n3);

    int k0 = (__builtin_bit_cast(int, av0) & ~0xFF) | (lane << 2) | 0;
    int k1 = (__builtin_bit_cast(int, av1) & ~0xFF) | (lane << 2) | 1;
    int k2 = (__builtin_bit_cast(int, av2) & ~0xFF) | (lane << 2) | 2;
    int k3 = v3 ? ((__builtin_bit_cast(int, av3) & ~0xFF) | (lane << 2) | 3) : 0;

    float mass = 0.f;
    #pragma unroll
    for (int k = 0; k < 9; ++k){
      int gk = wimax_all(max(max(k0, k1), max(k2, k3)));
      mass += __builtin_bit_cast(float, gk & ~0xFF);
      int gl = (gk >> 2) & 63, gq = gk & 3;
      if (lane == gl){
        if      (gq == 0) k0 = 0;
        else if (gq == 1) k1 = 0;
        else if (gq == 2) k2 = 0;
        else              k3 = 0;
      }
    }
    if (lane == 0) __builtin_nontemporal_store(mass, outK + (size_t)b*12 + m);
  }

  // ---- E: U[mh][c] = sum_n A[mh][n]*T[n][c] via MFMA (waves 0..2, 16 mh-rows each) ----
  if (h < 3){
    f32x4 u0 = {0,0,0,0}, u1 = {0,0,0,0};
    const int arow = h*16 + r15;
    // within-row half offsets for Ts16 column gathers (chunk slot constant per lane)
    const int o0 = ((((r15>>3)     + g) & 3) << 3) + (r15 & 7);   // c = r15
    const int o1 = ((((r15>>3) + 2 + g) & 3) << 3) + (r15 & 7);   // c = 16 + r15
    #pragma unroll
    for (int ks = 0; ks < 7; ++ks){
      const int nb = ks*32 + g*8;
      h8 af = *(const h8*)&As[arow*232 + nb];
      const _Float16* tb = &Ts16[nb*40];
      h8 b0, b1;
      #pragma unroll
      for (int j = 0; j < 8; ++j){
        b0[j] = tb[j*40 + o0];
        b1[j] = tb[j*40 + o1];
      }
      u0 = __builtin_amdgcn_mfma_f32_16x16x32_f16(af, b0, u0, 0, 0, 0);
      u1 = __builtin_amdgcn_mfma_f32_16x16x32_f16(af, b1, u1, 0, 0, 0);
    }
    #pragma unroll
    for (int r = 0; r < 4; ++r){
      U[(h*16 + g*4 + r)*36 + r15]      = u0[r];
      U[(h*16 + g*4 + r)*36 + 16 + r15] = u1[r];
    }
  }
  __syncthreads();

  // ---- S: S[m][d] = sum_c U[(d>>3)*12+m][c] * Wv[d][c]; write S out ----
  for (int md = tid; md < 384; md += 256){
    int m = md >> 5, d = md & 31, hh = d >> 3;
    const float4* Urow = (const float4*)(U + (hh*12 + m)*36);
    const float4* Wvr  = (const float4*)(Wv + d*32);
    float a = 0.f;
    #pragma unroll
    for (int q = 0; q < 8; ++q) a += dot4(Urow[q], Wvr[q]);
    Ss[md] = a;
    __builtin_nontemporal_store(a, outS + (size_t)b*384 + md);
  }
  __syncthreads();

  // ---- Z: Z[d] = bp[d] + sum_j Wp[d][j] * Ss[j] ----
  {
    int d = tid >> 3, j4 = tid & 7;
    const float4* Wp4 = (const float4*)(Wp + d*384);
    const float4* Ss4 = (const float4*)Ss;
    float a = 0.f;
    #pragma unroll
    for (int jj = 0; jj < 12; ++jj){
      int j = j4 + jj*8;
      a += dot4(Wp4[j], Ss4[j]);
    }
    red[tid] = a;
  }
  __syncthreads();
  if (tid < 32){
    float a = bp[tid];
    #pragma unroll
    for (int k = 0; k < 8; ++k) a += red[tid*8 + k];
    __builtin_nontemporal_store(a, outZ + (size_t)b*32 + tid);
  }
}

extern "C" void kernel_launch(void* const* d_in, const int* in_sizes, int n_in,
                              void* d_out, int out_size, void* d_ws, size_t ws_size,
                              hipStream_t stream)
{
  const float* T    = (const float*)d_in[0];
  const float* Q    = (const float*)d_in[1];
  const float* Wq   = (const float*)d_in[2];
  const float* Wk   = (const float*)d_in[3];
  const float* Wv   = (const float*)d_in[4];
  const float* Wp   = (const float*)d_in[5];
  const float* bp   = (const float*)d_in[6];
  const float* rpb  = (const float*)d_in[7];
  const float* qc   = (const float*)d_in[8];
  const float* kc   = (const float*)d_in[9];
  _Float16* G16    = (_Float16*)d_ws;
  _Float16* rpbc16 = (_Float16*)((char*)d_ws + 4096);
  float* outp = (float*)d_out;

  prologue_kernel<<<40, 256, 0, stream>>>(Q, Wq, Wk, rpb, qc, kc, G16, rpbc16);
  fused_main<<<4096, 256, 0, stream>>>(T, Wv, Wp, bp, G16, rpbc16, outp);
}

// Round 8
// 77.476 us; speedup vs baseline: 11.8303x; 1.1213x over previous
//
#include <hip/hip_runtime.h>
#include <math.h>

// B=4096, N=196, D=32, M=12, NH=4, DH=8, H=W=14
// outputs (flat f32): Z[4096*32] | A_maps[4096*12*196] | head_energy[4096*12*4] | S[4096*12*32] | topk_mass[4096*12]
// ws layout (bytes): G16 fp16[48*32] @0 | rpbc32 f32[48*208] @4096 (pad cols 196..207 = -60000)

typedef float f32x4 __attribute__((ext_vector_type(4)));
typedef float f32x2 __attribute__((ext_vector_type(2)));
typedef _Float16 h2  __attribute__((ext_vector_type(2)));
typedef _Float16 h4v __attribute__((ext_vector_type(4)));
typedef _Float16 h8  __attribute__((ext_vector_type(8)));
typedef __fp16 fp16x2 __attribute__((ext_vector_type(2)));

__device__ __forceinline__ h2 cvt_pk(float a, float b){
  fp16x2 r = __builtin_amdgcn_cvt_pkrtz(a, b);
  return __builtin_bit_cast(h2, r);
}

__device__ __forceinline__ float dot4(float4 a, float4 b){
  return a.x*b.x + a.y*b.y + a.z*b.z + a.w*b.w;
}

// ---- DPP int-max reduction (topk) ----
template<int CTRL>
__device__ __forceinline__ int idpp(int x, int id){
  return __builtin_amdgcn_update_dpp(id, x, CTRL, 0xF, 0xF, false);
}
__device__ __forceinline__ int wimax_all(int x){
  const int ID = 0;
  x = max(x, idpp<0x111>(x, ID));
  x = max(x, idpp<0x112>(x, ID));
  x = max(x, idpp<0x114>(x, ID));
  x = max(x, idpp<0x118>(x, ID));
  x = max(x, idpp<0x142>(x, ID));
  x = max(x, idpp<0x143>(x, ID));
  return __builtin_amdgcn_readlane(x, 63);
}

// ---------------- prologue: G16 fp16; rpbc32 f32 padded ----------------
__global__ void prologue_kernel(const float* __restrict__ Q, const float* __restrict__ Wq,
                                const float* __restrict__ Wk, const float* __restrict__ rpb,
                                const float* __restrict__ qc, const float* __restrict__ kc,
                                _Float16* __restrict__ G16, float* __restrict__ rpbc32)
{
  __shared__ float Qp[384];
  const int tid = threadIdx.x;
  const int bid = blockIdx.x;

  if (bid == 0){
    for (int i = tid; i < 384; i += 256){
      int m = i >> 5, d = i & 31;
      float a = 0.f;
      #pragma unroll
      for (int c = 0; c < 32; ++c) a += Q[m*32+c] * Wq[d*32+c];
      Qp[i] = a;
    }
    __syncthreads();
    const float s = 0.35355339059327373f; // 1/sqrt(8)
    for (int i = tid; i < 1536; i += 256){
      int hm = i >> 5, c = i & 31;
      int hh = hm / 12, mm = hm - 12*hh;
      float a = 0.f;
      #pragma unroll
      for (int dh = 0; dh < 8; ++dh) a += Qp[mm*32 + hh*8 + dh] * Wk[(hh*8+dh)*32 + c];
      G16[i] = (_Float16)(a * s);
    }
  }
  int i = bid*256 + tid;
  if (i < 9984){                       // 48 rows x 208 cols
    int mh = i / 208, n = i - mh*208;
    float v;
    if (n < 196){
      int hh = mh / 12, mm = mh - 12*hh;
      float dy = qc[2*mm]   - kc[2*n];
      float dx = qc[2*mm+1] - kc[2*n+1];
      int iy = (int)rintf(dy) + 13; iy = iy < 0 ? 0 : (iy > 26 ? 26 : iy);
      int ix = (int)rintf(dx) + 13; ix = ix < 0 ? 0 : (ix > 26 ? 26 : ix);
      v = rpb[hh*729 + iy*27 + ix];
    } else {
      v = -60000.0f;                   // pad: exp -> 0, never the max
    }
    rpbc32[i] = v;
  }
}

// TT layout: subtiled [nb][cb][4][16] halfs, nb-stride 128 halfs (UNPADDED: every
// [4][16] subtile is 128-B aligned, required by ds_read_b64_tr_b16 tile addressing).
// T[n][c] at (n>>2)*128 + (c>>4)*64 + (n&3)*16 + (c&15).
__device__ __forceinline__ int ttoff(int n, int c8){   // c8 = chunk of 8 halfs
  return (n>>2)*128 + ((c8>>1)<<6) + ((n&3)<<4) + ((c8&1)<<3);
}

// ---------------- fully fused kernel: one block per batch element ----------------
__global__ __launch_bounds__(256, 3) void fused_main(
    const float* __restrict__ T, const float* __restrict__ Wv, const float* __restrict__ Wp,
    const float* __restrict__ bp, const _Float16* __restrict__ G16,
    const float* __restrict__ rpbc32, float* __restrict__ out)
{
  // TT:14336B @0 | As:22272B @14336 | U:6912B @36608 ; Ss aliases TT (dead after E)
  __shared__ __align__(128) char smem[43520];
  _Float16* TT = (_Float16*)smem;                 // [56 nb][128] halfs
  _Float16* As = (_Float16*)(smem + 14336);       // [48][232] halfs
  float*    U  = (float*)(smem + 36608);          // [48][36] f32
  float*    Ss = (float*)smem;                    // [384] f32 (alias)

  const int b    = blockIdx.x;
  const int tid  = threadIdx.x;
  const int lane = tid & 63;
  const int h    = tid >> 6;       // wave id
  const int r15  = lane & 15;
  const int g    = lane >> 4;

  float* outZ = out;                       // [4096][32]
  float* outA = out + 131072;              // [4096][12][196]
  float* outE = out + 9764864;             // [4096][12][4]
  float* outS = out + 9961472;             // [4096][12][32]
  float* outK = out + 11534336;            // [4096][12]

  // ---- A: stage T -> fp16 subtiled LDS; zero rows 196..223 ----
  const float* Tb = T + (size_t)b*6272;
  #pragma unroll
  for (int ii = 0; ii < 3; ++ii){
    int i = tid + ii*256;                  // n < 192
    int n = i >> 2, c8 = i & 3;
    const f32x4* src = (const f32x4*)(Tb + n*32 + c8*8);
    f32x4 v0 = __builtin_nontemporal_load(src);
    f32x4 v1 = __builtin_nontemporal_load(src + 1);
    h2 p0 = cvt_pk(v0[0], v0[1]);
    h2 p1 = cvt_pk(v0[2], v0[3]);
    h2 p2 = cvt_pk(v1[0], v1[1]);
    h2 p3 = cvt_pk(v1[2], v1[3]);
    h4v lo = __builtin_shufflevector(p0, p1, 0,1,2,3);
    h4v hi = __builtin_shufflevector(p2, p3, 0,1,2,3);
    *(h8*)&TT[ttoff(n, c8)] = __builtin_shufflevector(lo, hi, 0,1,2,3,4,5,6,7);
  }
  if (tid < 128){
    int i = 768 + tid;                     // n = 192..223
    int n = i >> 2, c8 = i & 3;
    h8 hv = {0,0,0,0,0,0,0,0};
    if (n < 196){
      const f32x4* src = (const f32x4*)(Tb + n*32 + c8*8);
      f32x4 v0 = __builtin_nontemporal_load(src);
      f32x4 v1 = __builtin_nontemporal_load(src + 1);
      h2 p0 = cvt_pk(v0[0], v0[1]);
      h2 p1 = cvt_pk(v0[2], v0[3]);
      h2 p2 = cvt_pk(v1[0], v1[1]);
      h2 p3 = cvt_pk(v1[2], v1[3]);
      h4v lo = __builtin_shufflevector(p0, p1, 0,1,2,3);
      h4v hi = __builtin_shufflevector(p2, p3, 0,1,2,3);
      hv = __builtin_shufflevector(lo, hi, 0,1,2,3,4,5,6,7);
    }
    *(h8*)&TT[ttoff(n, c8)] = hv;
  }
  // zero As cols [208,224)
  if (tid < 96){
    int row = tid >> 1, part = tid & 1;
    h8 z = {0,0,0,0,0,0,0,0};
    *(h8*)&As[row*232 + 208 + part*8] = z;
  }

  // B-frag (G row) + rpb f32 accumulator init (global loads before the barrier)
  const int mhB = h*12 + (r15 < 12 ? r15 : 11);
  h8 bfrag = *(const h8*)(G16 + mhB*32 + g*8);
  f32x4 acc[13];
  #pragma unroll
  for (int t = 0; t < 13; ++t)
    acc[t] = *(const f32x4*)(rpbc32 + mhB*208 + t*16 + g*4);
  __syncthreads();

  // ---- B: content via MFMA.  C[n][mh]: n = t*16 + g*4 + r, mh col = r15. ----
  const int rowoff = ((r15>>2)*128) + ((r15&3)<<4) + ((g>>1)<<6) + ((g&1)<<3);
  #pragma unroll
  for (int t = 0; t < 13; ++t){
    h8 af = *(const h8*)&TT[rowoff + t*512];
    acc[t] = __builtin_amdgcn_mfma_f32_16x16x32_f16(af, bfrag, acc[t], 0, 0, 0);
  }

  // per-lane softmax over 52 n-values + cross-lane combine (lanes sharing r15)
  float mx = -1e30f;
  #pragma unroll
  for (int t = 0; t < 13; ++t)
    mx = fmaxf(mx, fmaxf(fmaxf(acc[t][0], acc[t][1]), fmaxf(acc[t][2], acc[t][3])));
  mx = fmaxf(mx, __shfl_xor(mx, 16));
  mx = fmaxf(mx, __shfl_xor(mx, 32));
  float se = 0.f, te = 0.f;
  #pragma unroll
  for (int t = 0; t < 13; ++t){
    #pragma unroll
    for (int r = 0; r < 4; ++r){
      float d = acc[t][r] - mx;
      float e = __expf(d);
      se += e; te += d*e;
      acc[t][r] = e;
    }
  }
  se += __shfl_xor(se, 16); se += __shfl_xor(se, 32);
  te += __shfl_xor(te, 16); te += __shfl_xor(te, 32);
  const float inv = 1.f / se;
  if (r15 < 12){
    #pragma unroll
    for (int t = 0; t < 13; ++t){
      h2 w0 = cvt_pk(acc[t][0]*inv, acc[t][1]*inv);
      h2 w1 = cvt_pk(acc[t][2]*inv, acc[t][3]*inv);
      *(h4v*)&As[mhB*232 + t*16 + g*4] = __builtin_shufflevector(w0, w1, 0,1,2,3);
    }
    if (g == 0){
      const float LOGN_INV = 0.18946127f; // 1/ln(196)
      outE[(size_t)b*48 + r15*4 + h] = 1.0f + (te*inv - __logf(se)) * LOGN_INV;
    }
  }
  __syncthreads();

  // ---- E: U[mh][c] = sum_n A[mh][n]*T[n][c] via MFMA + ds_read_b64_tr_b16 (waves 0..2) ----
  if (h < 3){
    f32x4 u0 = {0,0,0,0}, u1 = {0,0,0,0};
    const int arow = h*16 + r15;
    // lane vaddr = 128B-aligned subtile base + (lane&15)*8 bytes (own b64 slot);
    // tr delivers column (vaddr&127)>>3 = r15 of the [4][16] subtile.
    unsigned A0 = (unsigned)(size_t)&TT[0] + (unsigned)(g*512 + r15*8);
    #pragma unroll
    for (int ks = 0; ks < 7; ++ks){
      h8 af = *(const h8*)&As[arow*232 + ks*32 + g*8];
      h4v t0, t1, t2, t3;
      // B[k=n][j=c]: lane (r15,g) gets cols c=r15 (+16) of rows n=ks*32+g*8+0..7
      asm volatile("ds_read_b64_tr_b16 %0, %1"            : "=v"(t0) : "v"(A0));  // nb+0, cb0
      asm volatile("ds_read_b64_tr_b16 %0, %1 offset:256" : "=v"(t1) : "v"(A0));  // nb+1, cb0
      asm volatile("ds_read_b64_tr_b16 %0, %1 offset:128" : "=v"(t2) : "v"(A0));  // nb+0, cb1
      asm volatile("ds_read_b64_tr_b16 %0, %1 offset:384" : "=v"(t3) : "v"(A0));  // nb+1, cb1
      asm volatile("s_waitcnt lgkmcnt(0)" ::: "memory");
      __builtin_amdgcn_sched_barrier(0);
      h8 b0 = __builtin_shufflevector(t0, t1, 0,1,2,3,4,5,6,7);
      h8 b1 = __builtin_shufflevector(t2, t3, 0,1,2,3,4,5,6,7);
      u0 = __builtin_amdgcn_mfma_f32_16x16x32_f16(af, b0, u0, 0, 0, 0);
      u1 = __builtin_amdgcn_mfma_f32_16x16x32_f16(af, b1, u1, 0, 0, 0);
      A0 += 2048;   // next 8 nb-blocks (32 rows)
    }
    #pragma unroll
    for (int r = 0; r < 4; ++r){
      U[(h*16 + g*4 + r)*36 + r15]      = u0[r];
      U[(h*16 + g*4 + r)*36 + 16 + r15] = u1[r];
    }
  }

  // ---- C: A_avg, A_maps, top-9 mass. lane -> 4 consecutive n; 3 interleaved DPP chains ----
  {
    const bool act = (lane < 49);
    const int nb4 = lane * 4;
    int K00=0,K01=0,K02=0,K03=0, K10=0,K11=0,K12=0,K13=0, K20=0,K21=0,K22=0,K23=0;
    float mass0=0.f, mass1=0.f, mass2=0.f;
    const int m0 = h, m1 = h+4, m2 = h+8;

    #pragma unroll
    for (int mi = 0; mi < 3; ++mi){
      int m = (mi==0) ? m0 : ((mi==1) ? m1 : m2);
      if (act){
        h4v s0 = *(const h4v*)&As[(     m)*232 + nb4];
        h4v s1 = *(const h4v*)&As[(12 + m)*232 + nb4];
        h4v s2 = *(const h4v*)&As[(24 + m)*232 + nb4];
        h4v s3 = *(const h4v*)&As[(36 + m)*232 + nb4];
        h4v sh = (s0 + s1) + (s2 + s3);          // packed fp16 adds
        float a0 = 0.25f*(float)sh[0], a1 = 0.25f*(float)sh[1];
        float a2 = 0.25f*(float)sh[2], a3 = 0.25f*(float)sh[3];
        float* amrow = outA + (size_t)b*2352 + m*196 + nb4;
        f32x2 o0 = {a0, a1}, o1 = {a2, a3};
        __builtin_nontemporal_store(o0, (f32x2*)amrow);
        __builtin_nontemporal_store(o1, (f32x2*)(amrow + 2));
        int kk0 = (__builtin_bit_cast(int, a0) & ~0xFF) | (lane << 2) | 0;
        int kk1 = (__builtin_bit_cast(int, a1) & ~0xFF) | (lane << 2) | 1;
        int kk2 = (__builtin_bit_cast(int, a2) & ~0xFF) | (lane << 2) | 2;
        int kk3 = (__builtin_bit_cast(int, a3) & ~0xFF) | (lane << 2) | 3;
        if (mi == 0){ K00=kk0; K01=kk1; K02=kk2; K03=kk3; }
        else if (mi == 1){ K10=kk0; K11=kk1; K12=kk2; K13=kk3; }
        else { K20=kk0; K21=kk1; K22=kk2; K23=kk3; }
      }
    }
    #pragma unroll
    for (int k = 0; k < 9; ++k){
      int g0 = wimax_all(max(max(K00,K01), max(K02,K03)));
      int g1 = wimax_all(max(max(K10,K11), max(K12,K13)));
      int g2 = wimax_all(max(max(K20,K21), max(K22,K23)));
      mass0 += __builtin_bit_cast(float, g0 & ~0xFF);
      mass1 += __builtin_bit_cast(float, g1 & ~0xFF);
      mass2 += __builtin_bit_cast(float, g2 & ~0xFF);
      if (lane == ((g0 >> 2) & 63)){
        int q = g0 & 3;
        if (q==0) K00=0; else if (q==1) K01=0; else if (q==2) K02=0; else K03=0;
      }
      if (lane == ((g1 >> 2) & 63)){
        int q = g1 & 3;
        if (q==0) K10=0; else if (q==1) K11=0; else if (q==2) K12=0; else K13=0;
      }
      if (lane == ((g2 >> 2) & 63)){
        int q = g2 & 3;
        if (q==0) K20=0; else if (q==1) K21=0; else if (q==2) K22=0; else K23=0;
      }
    }
    if (lane == 0){
      __builtin_nontemporal_store(mass0, outK + (size_t)b*12 + m0);
      __builtin_nontemporal_store(mass1, outK + (size_t)b*12 + m1);
      __builtin_nontemporal_store(mass2, outK + (size_t)b*12 + m2);
    }
  }
  __syncthreads();

  // ---- S: S[m][d] = sum_c U[(d>>3)*12+m][c] * Wv[d][c]; write S out + Ss(LDS) ----
  for (int md = tid; md < 384; md += 256){
    int m = md >> 5, d = md & 31, hh = d >> 3;
    const float4* Urow = (const float4*)(U + (hh*12 + m)*36);
    const float4* Wvr  = (const float4*)(Wv + d*32);
    float a = 0.f;
    #pragma unroll
    for (int q = 0; q < 8; ++q) a += dot4(Urow[q], Wvr[q]);
    Ss[md] = a;
    __builtin_nontemporal_store(a, outS + (size_t)b*384 + md);
  }
  __syncthreads();

  // ---- Z: Z[d] = bp[d] + sum_j Wp[d][j] * Ss[j]  (8-lane shuffle reduce) ----
  {
    int d = tid >> 3, j4 = tid & 7;
    const float4* Wp4 = (const float4*)(Wp + d*384);
    const float4* Ss4 = (const float4*)Ss;
    float a = 0.f;
    #pragma unroll
    for (int jj = 0; jj < 12; ++jj){
      int j = j4 + jj*8;
      a += dot4(Wp4[j], Ss4[j]);
    }
    a += __shfl_xor(a, 1);
    a += __shfl_xor(a, 2);
    a += __shfl_xor(a, 4);
    if (j4 == 0)
      __builtin_nontemporal_store(bp[d] + a, outZ + (size_t)b*32 + d);
  }
}

extern "C" void kernel_launch(void* const* d_in, const int* in_sizes, int n_in,
                              void* d_out, int out_size, void* d_ws, size_t ws_size,
                              hipStream_t stream)
{
  const float* T    = (const float*)d_in[0];
  const float* Q    = (const float*)d_in[1];
  const float* Wq   = (const float*)d_in[2];
  const float* Wk   = (const float*)d_in[3];
  const float* Wv   = (const float*)d_in[4];
  const float* Wp   = (const float*)d_in[5];
  const float* bp   = (const float*)d_in[6];
  const float* rpb  = (const float*)d_in[7];
  const float* qc   = (const float*)d_in[8];
  const float* kc   = (const float*)d_in[9];
  _Float16* G16  = (_Float16*)d_ws;
  float* rpbc32  = (float*)((char*)d_ws + 4096);
  float* outp = (float*)d_out;

  prologue_kernel<<<40, 256, 0, stream>>>(Q, Wq, Wk, rpb, qc, kc, G16, rpbc32);
  fused_main<<<4096, 256, 0, stream>>>(T, Wv, Wp, bp, G16, rpbc32, outp);
}

// Round 9
// 70.705 us; speedup vs baseline: 12.9632x; 1.0958x over previous
//
#include <hip/hip_runtime.h>
#include <math.h>

// B=4096, N=196, D=32, M=12, NH=4, DH=8, H=W=14
// outputs (flat f32): Z[4096*32] | A_maps[4096*12*196] | head_energy[4096*12*4] | S[4096*12*32] | topk_mass[4096*12]
// ws layout (bytes): G16 fp16[48*32] @0 | rpbc32 f32[48*208] @4096 (pad cols 196..207 = -60000)

typedef float f32x4 __attribute__((ext_vector_type(4)));
typedef float f32x2 __attribute__((ext_vector_type(2)));
typedef _Float16 h2  __attribute__((ext_vector_type(2)));
typedef _Float16 h4v __attribute__((ext_vector_type(4)));
typedef _Float16 h8  __attribute__((ext_vector_type(8)));
typedef __fp16 fp16x2 __attribute__((ext_vector_type(2)));

__device__ __forceinline__ h2 cvt_pk(float a, float b){
  fp16x2 r = __builtin_amdgcn_cvt_pkrtz(a, b);
  return __builtin_bit_cast(h2, r);
}

__device__ __forceinline__ float dot4(float4 a, float4 b){
  return a.x*b.x + a.y*b.y + a.z*b.z + a.w*b.w;
}

// ---- DPP int-max reduction (topk) ----
template<int CTRL>
__device__ __forceinline__ int idpp(int x, int id){
  return __builtin_amdgcn_update_dpp(id, x, CTRL, 0xF, 0xF, false);
}
__device__ __forceinline__ int wimax_all(int x){
  const int ID = 0;
  x = max(x, idpp<0x111>(x, ID));
  x = max(x, idpp<0x112>(x, ID));
  x = max(x, idpp<0x114>(x, ID));
  x = max(x, idpp<0x118>(x, ID));
  x = max(x, idpp<0x142>(x, ID));
  x = max(x, idpp<0x143>(x, ID));
  return __builtin_amdgcn_readlane(x, 63);
}

// ---------------- prologue: G16 fp16; rpbc32 f32 padded ----------------
__global__ void prologue_kernel(const float* __restrict__ Q, const float* __restrict__ Wq,
                                const float* __restrict__ Wk, const float* __restrict__ rpb,
                                const float* __restrict__ qc, const float* __restrict__ kc,
                                _Float16* __restrict__ G16, float* __restrict__ rpbc32)
{
  __shared__ float Qp[384];
  const int tid = threadIdx.x;
  const int bid = blockIdx.x;

  if (bid == 0){
    for (int i = tid; i < 384; i += 256){
      int m = i >> 5, d = i & 31;
      float a = 0.f;
      #pragma unroll
      for (int c = 0; c < 32; ++c) a += Q[m*32+c] * Wq[d*32+c];
      Qp[i] = a;
    }
    __syncthreads();
    const float s = 0.35355339059327373f; // 1/sqrt(8)
    for (int i = tid; i < 1536; i += 256){
      int hm = i >> 5, c = i & 31;
      int hh = hm / 12, mm = hm - 12*hh;
      float a = 0.f;
      #pragma unroll
      for (int dh = 0; dh < 8; ++dh) a += Qp[mm*32 + hh*8 + dh] * Wk[(hh*8+dh)*32 + c];
      G16[i] = (_Float16)(a * s);
    }
  }
  int i = bid*256 + tid;
  if (i < 9984){                       // 48 rows x 208 cols
    int mh = i / 208, n = i - mh*208;
    float v;
    if (n < 196){
      int hh = mh / 12, mm = mh - 12*hh;
      float dy = qc[2*mm]   - kc[2*n];
      float dx = qc[2*mm+1] - kc[2*n+1];
      int iy = (int)rintf(dy) + 13; iy = iy < 0 ? 0 : (iy > 26 ? 26 : iy);
      int ix = (int)rintf(dx) + 13; ix = ix < 0 ? 0 : (ix > 26 ? 26 : ix);
      v = rpb[hh*729 + iy*27 + ix];
    } else {
      v = -60000.0f;                   // pad: exp -> 0, never the max
    }
    rpbc32[i] = v;
  }
}

// TT layout: subtiled [nb][cb][4][16] halfs, nb-stride 128 halfs (UNPADDED: every
// [4][16] subtile is 128-B aligned, required by ds_read_b64_tr_b16 tile addressing).
// T[n][c] at (n>>2)*128 + (c>>4)*64 + (n&3)*16 + (c&15).
__device__ __forceinline__ int ttoff(int n, int c8){   // c8 = chunk of 8 halfs
  return (n>>2)*128 + ((c8>>1)<<6) + ((n&3)<<4) + ((c8&1)<<3);
}

// ---------------- fully fused kernel: one block per batch element ----------------
__global__ __launch_bounds__(256, 4) void fused_main(
    const float* __restrict__ T, const float* __restrict__ Wv, const float* __restrict__ Wp,
    const float* __restrict__ bp, const _Float16* __restrict__ G16,
    const float* __restrict__ rpbc32, float* __restrict__ out)
{
  // TT:14336B @0 | As:22272B @14336.  After the post-E/C barrier TT is dead and is
  // re-used: U [48][36] f32 @0 (6912B) | Ss [384] f32 @7168 (1536B).
  // Total LDS 36608B -> 4 blocks/CU.
  __shared__ __align__(128) char smem[36608];
  _Float16* TT = (_Float16*)smem;                 // [56 nb][128] halfs
  _Float16* As = (_Float16*)(smem + 14336);       // [48][232] halfs
  float*    U  = (float*)smem;                    // [48][36] f32 (alias, after barrier)
  float*    Ss = (float*)(smem + 7168);           // [384] f32 (alias)

  const int b    = blockIdx.x;
  const int tid  = threadIdx.x;
  const int lane = tid & 63;
  const int h    = tid >> 6;       // wave id
  const int r15  = lane & 15;
  const int g    = lane >> 4;

  float* outZ = out;                       // [4096][32]
  float* outA = out + 131072;              // [4096][12][196]
  float* outE = out + 9764864;             // [4096][12][4]
  float* outS = out + 9961472;             // [4096][12][32]
  float* outK = out + 11534336;            // [4096][12]

  // ---- A: stage T -> fp16 subtiled LDS; zero rows 196..223 ----
  const float* Tb = T + (size_t)b*6272;
  #pragma unroll
  for (int ii = 0; ii < 3; ++ii){
    int i = tid + ii*256;                  // n < 192
    int n = i >> 2, c8 = i & 3;
    const f32x4* src = (const f32x4*)(Tb + n*32 + c8*8);
    f32x4 v0 = __builtin_nontemporal_load(src);
    f32x4 v1 = __builtin_nontemporal_load(src + 1);
    h2 p0 = cvt_pk(v0[0], v0[1]);
    h2 p1 = cvt_pk(v0[2], v0[3]);
    h2 p2 = cvt_pk(v1[0], v1[1]);
    h2 p3 = cvt_pk(v1[2], v1[3]);
    h4v lo = __builtin_shufflevector(p0, p1, 0,1,2,3);
    h4v hi = __builtin_shufflevector(p2, p3, 0,1,2,3);
    *(h8*)&TT[ttoff(n, c8)] = __builtin_shufflevector(lo, hi, 0,1,2,3,4,5,6,7);
  }
  if (tid < 128){
    int i = 768 + tid;                     // n = 192..223
    int n = i >> 2, c8 = i & 3;
    h8 hv = {0,0,0,0,0,0,0,0};
    if (n < 196){
      const f32x4* src = (const f32x4*)(Tb + n*32 + c8*8);
      f32x4 v0 = __builtin_nontemporal_load(src);
      f32x4 v1 = __builtin_nontemporal_load(src + 1);
      h2 p0 = cvt_pk(v0[0], v0[1]);
      h2 p1 = cvt_pk(v0[2], v0[3]);
      h2 p2 = cvt_pk(v1[0], v1[1]);
      h2 p3 = cvt_pk(v1[2], v1[3]);
      h4v lo = __builtin_shufflevector(p0, p1, 0,1,2,3);
      h4v hi = __builtin_shufflevector(p2, p3, 0,1,2,3);
      hv = __builtin_shufflevector(lo, hi, 0,1,2,3,4,5,6,7);
    }
    *(h8*)&TT[ttoff(n, c8)] = hv;
  }
  // zero As cols [208,224)
  if (tid < 96){
    int row = tid >> 1, part = tid & 1;
    h8 z = {0,0,0,0,0,0,0,0};
    *(h8*)&As[row*232 + 208 + part*8] = z;
  }

  // B-frag (G row) + rpb f32 accumulator init (global loads before the barrier)
  const int mhB = h*12 + (r15 < 12 ? r15 : 11);
  h8 bfrag = *(const h8*)(G16 + mhB*32 + g*8);
  f32x4 acc[13];
  #pragma unroll
  for (int t = 0; t < 13; ++t)
    acc[t] = *(const f32x4*)(rpbc32 + mhB*208 + t*16 + g*4);
  __syncthreads();

  // ---- B: content via MFMA.  C[n][mh]: n = t*16 + g*4 + r, mh col = r15. ----
  const int rowoff = ((r15>>2)*128) + ((r15&3)<<4) + ((g>>1)<<6) + ((g&1)<<3);
  #pragma unroll
  for (int t = 0; t < 13; ++t){
    h8 af = *(const h8*)&TT[rowoff + t*512];
    acc[t] = __builtin_amdgcn_mfma_f32_16x16x32_f16(af, bfrag, acc[t], 0, 0, 0);
  }

  // per-lane softmax over 52 n-values + cross-lane combine (lanes sharing r15)
  float mx = -1e30f;
  #pragma unroll
  for (int t = 0; t < 13; ++t)
    mx = fmaxf(mx, fmaxf(fmaxf(acc[t][0], acc[t][1]), fmaxf(acc[t][2], acc[t][3])));
  mx = fmaxf(mx, __shfl_xor(mx, 16));
  mx = fmaxf(mx, __shfl_xor(mx, 32));
  float se = 0.f, te = 0.f;
  #pragma unroll
  for (int t = 0; t < 13; ++t){
    #pragma unroll
    for (int r = 0; r < 4; ++r){
      float d = acc[t][r] - mx;
      float e = __expf(d);
      se += e; te += d*e;
      acc[t][r] = e;
    }
  }
  se += __shfl_xor(se, 16); se += __shfl_xor(se, 32);
  te += __shfl_xor(te, 16); te += __shfl_xor(te, 32);
  const float inv = 1.f / se;
  if (r15 < 12){
    #pragma unroll
    for (int t = 0; t < 13; ++t){
      h2 w0 = cvt_pk(acc[t][0]*inv, acc[t][1]*inv);
      h2 w1 = cvt_pk(acc[t][2]*inv, acc[t][3]*inv);
      *(h4v*)&As[mhB*232 + t*16 + g*4] = __builtin_shufflevector(w0, w1, 0,1,2,3);
    }
    if (g == 0){
      const float LOGN_INV = 0.18946127f; // 1/ln(196)
      outE[(size_t)b*48 + r15*4 + h] = 1.0f + (te*inv - __logf(se)) * LOGN_INV;
    }
  }
  __syncthreads();

  // ---- E: U[mh][c] = sum_n A[mh][n]*T[n][c] via MFMA + ds_read_b64_tr_b16 (waves 0..2).
  //      Result stays in registers; written to LDS only after TT is dead. ----
  f32x4 u0 = {0,0,0,0}, u1 = {0,0,0,0};
  if (h < 3){
    const int arow = h*16 + r15;
    // lane vaddr = 128B-aligned subtile base + (lane&15)*8 bytes (own b64 slot);
    // tr delivers column (vaddr&127)>>3 = r15 of the [4][16] subtile.
    unsigned A0 = (unsigned)(size_t)&TT[0] + (unsigned)(g*512 + r15*8);
    #pragma unroll
    for (int ks = 0; ks < 7; ++ks){
      h8 af = *(const h8*)&As[arow*232 + ks*32 + g*8];
      h4v t0, t1, t2, t3;
      // B[k=n][j=c]: lane (r15,g) gets cols c=r15 (+16) of rows n=ks*32+g*8+0..7
      asm volatile("ds_read_b64_tr_b16 %0, %1"            : "=v"(t0) : "v"(A0));  // nb+0, cb0
      asm volatile("ds_read_b64_tr_b16 %0, %1 offset:256" : "=v"(t1) : "v"(A0));  // nb+1, cb0
      asm volatile("ds_read_b64_tr_b16 %0, %1 offset:128" : "=v"(t2) : "v"(A0));  // nb+0, cb1
      asm volatile("ds_read_b64_tr_b16 %0, %1 offset:384" : "=v"(t3) : "v"(A0));  // nb+1, cb1
      asm volatile("s_waitcnt lgkmcnt(0)" ::: "memory");
      __builtin_amdgcn_sched_barrier(0);
      h8 b0 = __builtin_shufflevector(t0, t1, 0,1,2,3,4,5,6,7);
      h8 b1 = __builtin_shufflevector(t2, t3, 0,1,2,3,4,5,6,7);
      u0 = __builtin_amdgcn_mfma_f32_16x16x32_f16(af, b0, u0, 0, 0, 0);
      u1 = __builtin_amdgcn_mfma_f32_16x16x32_f16(af, b1, u1, 0, 0, 0);
      A0 += 2048;   // next 8 nb-blocks (32 rows)
    }
  }

  // ---- C: A_avg, A_maps, top-9 mass. lane -> 4 consecutive n; 3 interleaved DPP chains ----
  {
    const bool act = (lane < 49);
    const int nb4 = lane * 4;
    int K00=0,K01=0,K02=0,K03=0, K10=0,K11=0,K12=0,K13=0, K20=0,K21=0,K22=0,K23=0;
    float mass0=0.f, mass1=0.f, mass2=0.f;
    const int m0 = h, m1 = h+4, m2 = h+8;

    #pragma unroll
    for (int mi = 0; mi < 3; ++mi){
      int m = (mi==0) ? m0 : ((mi==1) ? m1 : m2);
      if (act){
        h4v s0 = *(const h4v*)&As[(     m)*232 + nb4];
        h4v s1 = *(const h4v*)&As[(12 + m)*232 + nb4];
        h4v s2 = *(const h4v*)&As[(24 + m)*232 + nb4];
        h4v s3 = *(const h4v*)&As[(36 + m)*232 + nb4];
        h4v sh = (s0 + s1) + (s2 + s3);          // packed fp16 adds
        float a0 = 0.25f*(float)sh[0], a1 = 0.25f*(float)sh[1];
        float a2 = 0.25f*(float)sh[2], a3 = 0.25f*(float)sh[3];
        float* amrow = outA + (size_t)b*2352 + m*196 + nb4;
        f32x2 o0 = {a0, a1}, o1 = {a2, a3};
        __builtin_nontemporal_store(o0, (f32x2*)amrow);
        __builtin_nontemporal_store(o1, (f32x2*)(amrow + 2));
        int kk0 = (__builtin_bit_cast(int, a0) & ~0xFF) | (lane << 2) | 0;
        int kk1 = (__builtin_bit_cast(int, a1) & ~0xFF) | (lane << 2) | 1;
        int kk2 = (__builtin_bit_cast(int, a2) & ~0xFF) | (lane << 2) | 2;
        int kk3 = (__builtin_bit_cast(int, a3) & ~0xFF) | (lane << 2) | 3;
        if (mi == 0){ K00=kk0; K01=kk1; K02=kk2; K03=kk3; }
        else if (mi == 1){ K10=kk0; K11=kk1; K12=kk2; K13=kk3; }
        else { K20=kk0; K21=kk1; K22=kk2; K23=kk3; }
      }
    }
    #pragma unroll
    for (int k = 0; k < 9; ++k){
      int g0 = wimax_all(max(max(K00,K01), max(K02,K03)));
      int g1 = wimax_all(max(max(K10,K11), max(K12,K13)));
      int g2 = wimax_all(max(max(K20,K21), max(K22,K23)));
      mass0 += __builtin_bit_cast(float, g0 & ~0xFF);
      mass1 += __builtin_bit_cast(float, g1 & ~0xFF);
      mass2 += __builtin_bit_cast(float, g2 & ~0xFF);
      if (lane == ((g0 >> 2) & 63)){
        int q = g0 & 3;
        if (q==0) K00=0; else if (q==1) K01=0; else if (q==2) K02=0; else K03=0;
      }
      if (lane == ((g1 >> 2) & 63)){
        int q = g1 & 3;
        if (q==0) K10=0; else if (q==1) K11=0; else if (q==2) K12=0; else K13=0;
      }
      if (lane == ((g2 >> 2) & 63)){
        int q = g2 & 3;
        if (q==0) K20=0; else if (q==1) K21=0; else if (q==2) K22=0; else K23=0;
      }
    }
    if (lane == 0){
      __builtin_nontemporal_store(mass0, outK + (size_t)b*12 + m0);
      __builtin_nontemporal_store(mass1, outK + (size_t)b*12 + m1);
      __builtin_nontemporal_store(mass2, outK + (size_t)b*12 + m2);
    }
  }
  __syncthreads();   // all TT reads (tr + content) and As reads done; TT is dead

  // ---- U-write: spill register U into the dead TT region ----
  if (h < 3){
    #pragma unroll
    for (int r = 0; r < 4; ++r){
      U[(h*16 + g*4 + r)*36 + r15]      = u0[r];
      U[(h*16 + g*4 + r)*36 + 16 + r15] = u1[r];
    }
  }
  __syncthreads();

  // ---- S: S[m][d] = sum_c U[(d>>3)*12+m][c] * Wv[d][c]; write S out + Ss(LDS) ----
  for (int md = tid; md < 384; md += 256){
    int m = md >> 5, d = md & 31, hh = d >> 3;
    const float4* Urow = (const float4*)(U + (hh*12 + m)*36);
    const float4* Wvr  = (const float4*)(Wv + d*32);
    float a = 0.f;
    #pragma unroll
    for (int q = 0; q < 8; ++q) a += dot4(Urow[q], Wvr[q]);
    Ss[md] = a;
    __builtin_nontemporal_store(a, outS + (size_t)b*384 + md);
  }
  __syncthreads();

  // ---- Z: Z[d] = bp[d] + sum_j Wp[d][j] * Ss[j]  (8-lane shuffle reduce) ----
  {
    int d = tid >> 3, j4 = tid & 7;
    const float4* Wp4 = (const float4*)(Wp + d*384);
    const float4* Ss4 = (const float4*)Ss;
    float a = 0.f;
    #pragma unroll
    for (int jj = 0; jj < 12; ++jj){
      int j = j4 + jj*8;
      a += dot4(Wp4[j], Ss4[j]);
    }
    a += __shfl_xor(a, 1);
    a += __shfl_xor(a, 2);
    a += __shfl_xor(a, 4);
    if (j4 == 0)
      __builtin_nontemporal_store(bp[d] + a, outZ + (size_t)b*32 + d);
  }
}

extern "C" void kernel_launch(void* const* d_in, const int* in_sizes, int n_in,
                              void* d_out, int out_size, void* d_ws, size_t ws_size,
                              hipStream_t stream)
{
  const float* T    = (const float*)d_in[0];
  const float* Q    = (const float*)d_in[1];
  const float* Wq   = (const float*)d_in[2];
  const float* Wk   = (const float*)d_in[3];
  const float* Wv   = (const float*)d_in[4];
  const float* Wp   = (const float*)d_in[5];
  const float* bp   = (const float*)d_in[6];
  const float* rpb  = (const float*)d_in[7];
  const float* qc   = (const float*)d_in[8];
  const float* kc   = (const float*)d_in[9];
  _Float16* G16  = (_Float16*)d_ws;
  float* rpbc32  = (float*)((char*)d_ws + 4096);
  float* outp = (float*)d_out;

  prologue_kernel<<<40, 256, 0, stream>>>(Q, Wq, Wk, rpb, qc, kc, G16, rpbc32);
  fused_main<<<4096, 256, 0, stream>>>(T, Wv, Wp, bp, G16, rpbc32, outp);
}